// Round 2
// baseline (1616.604 us; speedup 1.0000x reference)
//
#include <hip/hip_runtime.h>
#include <hip/hip_bf16.h>

// ContralateralAttention: feat(8,256,64,64) fp32.
// Tokens: t = b*4096 + y*64 + x_feat (x_feat in [0,64)), 32768 total.
// side0 queries: x_feat<32, memory = feat col 63-x'. side1: x_feat>=32, memory = col 31-x'.
// Mask: Manhattan radius 2 on (64,32) grid -> <=13 neighbors.

#define NTOK 32768

// ---------------- K1: QKV = X @ in_w.T + in_b  (32768x256 @ 256x768) ----------------
__global__ __launch_bounds__(256) void qkv_kernel(const float* __restrict__ feat,
                                                  const float* __restrict__ in_w,
                                                  const float* __restrict__ in_b,
                                                  float* __restrict__ qkv) {
    __shared__ float As[32][68];
    __shared__ float Bs[32][68];
    const int t0 = blockIdx.x * 64;
    const int j0 = blockIdx.y * 64;
    const int tid = threadIdx.x;
    const int b = t0 >> 12;
    const int sp = t0 & 4095;
    const int tm = (tid & 15) * 4;
    const int tn = (tid >> 4) * 4;
    float acc[4][4] = {};
    for (int k0 = 0; k0 < 256; k0 += 32) {
        {   // A: feat transposed access, coalesced over tokens
            const int tl = tid & 63;
            const int cb = tid >> 6;  // 0..3
            #pragma unroll
            for (int u = 0; u < 8; ++u) {
                int cl = cb + u * 4;
                As[cl][tl] = feat[((size_t)(b * 256 + k0 + cl) << 12) + sp + tl];
            }
        }
        {   // B: in_w[j][c] row-major, coalesced over c
            const int cl = tid & 31;
            const int jl0 = tid >> 5; // 0..7
            #pragma unroll
            for (int u = 0; u < 8; ++u) {
                int jl = jl0 + u * 8;
                Bs[cl][jl] = in_w[(size_t)(j0 + jl) * 256 + k0 + cl];
            }
        }
        __syncthreads();
        #pragma unroll
        for (int k = 0; k < 32; ++k) {
            float a[4], bb[4];
            #pragma unroll
            for (int i = 0; i < 4; ++i) a[i] = As[k][tm + i];
            #pragma unroll
            for (int j = 0; j < 4; ++j) bb[j] = Bs[k][tn + j];
            #pragma unroll
            for (int i = 0; i < 4; ++i)
                #pragma unroll
                for (int j = 0; j < 4; ++j)
                    acc[i][j] += a[i] * bb[j];
        }
        __syncthreads();
    }
    #pragma unroll
    for (int i = 0; i < 4; ++i) {
        int t = t0 + tm + i;
        #pragma unroll
        for (int j = 0; j < 4; ++j) {
            int jj = j0 + tn + j;
            qkv[(size_t)t * 768 + jj] = acc[i][j] + in_b[jj];
        }
    }
}

// ---------------- K2: sparse masked attention, one wave per (query token, head) ----------------
__global__ __launch_bounds__(256) void attn_kernel(const float* __restrict__ qkv,
                                                   float* __restrict__ ctx) {
    const int w = blockIdx.x * 4 + (threadIdx.x >> 6);
    const int lane = threadIdx.x & 63;
    const int head = w & 3;
    const int x = (w >> 2) & 31;
    const int y = (w >> 7) & 63;
    const int b = (w >> 13) & 7;
    const int side = (w >> 16) & 1;
    const int xq = side ? (32 + x) : x;
    const int tq = (b << 12) + (y << 6) + xq;

    const float qv = qkv[(size_t)tq * 768 + (head << 6) + lane];

    const int dyv[13] = {0, 0, 0, 0, 0, -1, -1, -1, 1, 1, 1, -2, 2};
    const int dxv[13] = {0, -1, 1, -2, 2, 0, -1, 1, 0, -1, 1, 0, 0};

    float sc[13];
    float m = -1e30f;
    #pragma unroll
    for (int i = 0; i < 13; ++i) {
        const int yy = y + dyv[i], xx = x + dxv[i];
        const bool ok = (yy >= 0 && yy < 64 && xx >= 0 && xx < 32); // wave-uniform
        float s = -1e30f;
        if (ok) {
            const int xm = side ? (31 - xx) : (63 - xx);
            const int tm = (b << 12) + (yy << 6) + xm;
            float p = qv * qkv[(size_t)tm * 768 + 256 + (head << 6) + lane];
            #pragma unroll
            for (int o = 1; o < 64; o <<= 1) p += __shfl_xor(p, o, 64);
            s = p * 0.125f;  // 1/sqrt(64)
        }
        sc[i] = s;
        m = fmaxf(m, s);
    }
    float l = 0.f, acc = 0.f;
    #pragma unroll
    for (int i = 0; i < 13; ++i) {
        const int yy = y + dyv[i], xx = x + dxv[i];
        const bool ok = (yy >= 0 && yy < 64 && xx >= 0 && xx < 32);
        if (ok) {
            const float p = __expf(sc[i] - m);
            l += p;
            const int xm = side ? (31 - xx) : (63 - xx);
            const int tm = (b << 12) + (yy << 6) + xm;
            acc += p * qkv[(size_t)tm * 768 + 512 + (head << 6) + lane];
        }
    }
    ctx[(size_t)tq * 256 + (head << 6) + lane] = acc / l;
}

// ---------------- K3: ctx2 = ctx @ out_w.T + out_b  (32768x256 @ 256x256) ----------------
__global__ __launch_bounds__(256) void outproj_kernel(const float* __restrict__ ctx,
                                                      const float* __restrict__ out_w,
                                                      const float* __restrict__ out_b,
                                                      float* __restrict__ ctx2) {
    __shared__ float As[32][68];
    __shared__ float Bs[32][68];
    const int t0 = blockIdx.x * 64;
    const int j0 = blockIdx.y * 64;
    const int tid = threadIdx.x;
    const int tm = (tid & 15) * 4;
    const int tn = (tid >> 4) * 4;
    float acc[4][4] = {};
    for (int k0 = 0; k0 < 256; k0 += 32) {
        {
            const int cl = tid & 31;
            const int tl0 = tid >> 5;
            #pragma unroll
            for (int u = 0; u < 8; ++u) {
                int tl = tl0 + u * 8;
                As[cl][tl] = ctx[(size_t)(t0 + tl) * 256 + k0 + cl];
            }
        }
        {
            const int cl = tid & 31;
            const int jl0 = tid >> 5;
            #pragma unroll
            for (int u = 0; u < 8; ++u) {
                int jl = jl0 + u * 8;
                Bs[cl][jl] = out_w[(size_t)(j0 + jl) * 256 + k0 + cl];
            }
        }
        __syncthreads();
        #pragma unroll
        for (int k = 0; k < 32; ++k) {
            float a[4], bb[4];
            #pragma unroll
            for (int i = 0; i < 4; ++i) a[i] = As[k][tm + i];
            #pragma unroll
            for (int j = 0; j < 4; ++j) bb[j] = Bs[k][tn + j];
            #pragma unroll
            for (int i = 0; i < 4; ++i)
                #pragma unroll
                for (int j = 0; j < 4; ++j)
                    acc[i][j] += a[i] * bb[j];
        }
        __syncthreads();
    }
    #pragma unroll
    for (int i = 0; i < 4; ++i) {
        int t = t0 + tm + i;
        #pragma unroll
        for (int j = 0; j < 4; ++j) {
            int jj = j0 + tn + j;
            ctx2[(size_t)t * 256 + jj] = acc[i][j] + out_b[jj];
        }
    }
}

// ---------------- K4: y = LN([qt,ctx2,|qt-ctx2|,qt*ctx2] @ proj_w.T + proj_b); relu; store ----------------
// tile: 32 tokens x full 256 outputs (LN needs the whole row). asym formed on the fly.
__global__ __launch_bounds__(256) void proj_ln_kernel(const float* __restrict__ feat,
                                                      const float* __restrict__ ctx2,
                                                      const float* __restrict__ proj_w,
                                                      const float* __restrict__ proj_b,
                                                      const float* __restrict__ ln_g,
                                                      const float* __restrict__ ln_b,
                                                      float* __restrict__ out) {
    __shared__ float qs[16][36];
    __shared__ float cs[16][36];
    __shared__ float Bs[16][260];
    __shared__ float ys[32][260];
    __shared__ float mu_s[32], inv_s[32];
    const int tid = threadIdx.x;
    const int t0 = blockIdx.x * 32;
    const int b = t0 >> 12;
    const int sp = t0 & 4095;
    const int tb = (tid & 7) * 4;    // 4 tokens
    const int jb = (tid >> 3) * 8;   // 8 outputs
    float acc[4][8] = {};

    for (int cb = 0; cb < 256; cb += 16) {
        __syncthreads();
        {   // qt tile (feat transposed access, coalesced over tokens)
            const int tl = tid & 31;
            const int cl = tid >> 5;  // 0..7
            #pragma unroll
            for (int u = 0; u < 2; ++u) {
                int c = cl + u * 8;
                qs[c][tl] = feat[((size_t)(b * 256 + cb + c) << 12) + sp + tl];
            }
        }
        {   // ctx2 tile (row-major, coalesced over channels)
            const int cl = tid & 15;
            const int tl0 = tid >> 4; // 0..15
            #pragma unroll
            for (int u = 0; u < 2; ++u) {
                int tl = tl0 + u * 16;
                cs[cl][tl] = ctx2[(size_t)(t0 + tl) * 256 + cb + cl];
            }
        }
        for (int g = 0; g < 4; ++g) {
            if (g) __syncthreads();
            {   // proj_w tile: 256 j x 16 k (k = g*256 + cb + kk)
                const int kk = tid & 15;
                const int jl0 = tid >> 4;
                #pragma unroll
                for (int u = 0; u < 16; ++u) {
                    int j = jl0 + u * 16;
                    Bs[kk][j] = proj_w[(size_t)j * 1024 + g * 256 + cb + kk];
                }
            }
            __syncthreads();
            #pragma unroll
            for (int k = 0; k < 16; ++k) {
                float a[4];
                #pragma unroll
                for (int i = 0; i < 4; ++i) {
                    float qv = qs[k][tb + i];
                    float cv = cs[k][tb + i];
                    a[i] = (g == 0) ? qv : (g == 1) ? cv
                         : (g == 2) ? fabsf(qv - cv) : qv * cv;
                }
                float bb[8];
                #pragma unroll
                for (int j = 0; j < 8; ++j) bb[j] = Bs[k][jb + j];
                #pragma unroll
                for (int i = 0; i < 4; ++i)
                    #pragma unroll
                    for (int j = 0; j < 8; ++j)
                        acc[i][j] += a[i] * bb[j];
            }
        }
    }
    __syncthreads();
    #pragma unroll
    for (int i = 0; i < 4; ++i)
        #pragma unroll
        for (int j = 0; j < 8; ++j)
            ys[tb + i][jb + j] = acc[i][j] + proj_b[jb + j];
    __syncthreads();
    {   // LN stats: 8 threads per token
        const int tt = tid >> 3, seg = tid & 7;
        float s = 0.f, ss = 0.f;
        #pragma unroll
        for (int j = 0; j < 32; ++j) {
            float v = ys[tt][seg * 32 + j];
            s += v; ss += v * v;
        }
        #pragma unroll
        for (int o = 1; o < 8; o <<= 1) {
            s += __shfl_xor(s, o, 8);
            ss += __shfl_xor(ss, o, 8);
        }
        if (seg == 0) {
            float mu = s * (1.f / 256.f);
            float var = ss * (1.f / 256.f) - mu * mu;
            mu_s[tt] = mu;
            inv_s[tt] = rsqrtf(var + 1e-5f);
        }
    }
    __syncthreads();
    {   // normalize + relu + coalesced transposed store
        // FIX (R1): was u < 8 -> only channels 0..63 written, channels 64..255
        // stayed zero => absmax == max|ref| == stub error. Need 32 iters so
        // j = j0 + 8u covers [0,256): 256 threads x 32 stores = 32 tok x 256 ch.
        const int tl = tid & 31;
        const int j0 = tid >> 5;
        const float mu = mu_s[tl], inv = inv_s[tl];
        #pragma unroll
        for (int u = 0; u < 32; ++u) {
            int j = j0 + u * 8;
            float v = (ys[tl][j] - mu) * inv * ln_g[j] + ln_b[j];
            out[((size_t)(b * 256 + j) << 12) + sp + tl] = fmaxf(v, 0.f);
        }
    }
}

extern "C" void kernel_launch(void* const* d_in, const int* in_sizes, int n_in,
                              void* d_out, int out_size, void* d_ws, size_t ws_size,
                              hipStream_t stream) {
    (void)in_sizes; (void)n_in; (void)out_size; (void)ws_size;
    const float* feat   = (const float*)d_in[0];
    const float* in_w   = (const float*)d_in[1];
    const float* in_b   = (const float*)d_in[2];
    const float* out_w  = (const float*)d_in[3];
    const float* out_b  = (const float*)d_in[4];
    const float* proj_w = (const float*)d_in[5];
    const float* proj_b = (const float*)d_in[6];
    const float* ln_g   = (const float*)d_in[7];
    const float* ln_b   = (const float*)d_in[8];
    float* out = (float*)d_out;

    float* qkv  = (float*)d_ws;                                   // 32768*768*4 = 96 MB
    float* ctx  = (float*)((char*)d_ws + (size_t)NTOK * 768 * 4); // 32 MB
    float* ctx2 = (float*)d_ws;                                   // aliases qkv (dead after attn)

    qkv_kernel    <<<dim3(NTOK / 64, 12), 256, 0, stream>>>(feat, in_w, in_b, qkv);
    attn_kernel   <<<dim3(131072 / 4),    256, 0, stream>>>(qkv, ctx);
    outproj_kernel<<<dim3(NTOK / 64, 4),  256, 0, stream>>>(ctx, out_w, out_b, ctx2);
    proj_ln_kernel<<<dim3(NTOK / 32),     256, 0, stream>>>(feat, ctx2, proj_w, proj_b,
                                                            ln_g, ln_b, out);
}

// Round 3
// 371.985 us; speedup vs baseline: 4.3459x; 4.3459x over previous
//
#include <hip/hip_runtime.h>
#include <hip/hip_bf16.h>

// ContralateralAttention, bf16-MFMA version.
// Tokens: t = b*4096 + y*64 + x (x in [0,64)), 32768 total.
// ws layout (MB = 1<<20), lifetime-packed, peak 113 MB:
//   Xbf   [  0, 16)   32768x256  bf16 token-major feat
//   wbf   [ 16, 17)   in_w(196608) | out_w(65536) | proj_w(262144) bf16
//   qkv   [ 17, 65)   32768x768  bf16            (dead after attn)
//   ctx   [ 65, 81)   32768x256  bf16            (dead after K3)
//   asym  [ 17, 81)   32768x1024 bf16  (aliases qkv+ctx)
//   ctx2  [ 81, 97)   32768x256  bf16            (dead after build_asym)
//   y     [ 81,113)   32768x256  f32   (aliases ctx2)

#define NTOK 32768

using bf16x8 = __attribute__((ext_vector_type(8))) short;
using f32x4  = __attribute__((ext_vector_type(4))) float;

// ---------------- prep: feat (b,c,sp) f32 -> Xbf (t=b*4096+sp, c) bf16 ----------------
__global__ __launch_bounds__(256) void transpose_cast(const float* __restrict__ feat,
                                                      __hip_bfloat16* __restrict__ X) {
    __shared__ float tile[32][33];
    const int b  = blockIdx.z;
    const int c0 = blockIdx.y * 32;
    const int sp0 = blockIdx.x * 32;
    const int tid = threadIdx.x;
    const int col = tid & 31, rowg = tid >> 5;  // 8 rows/pass
    #pragma unroll
    for (int u = 0; u < 4; ++u) {
        int cl = rowg + u * 8;
        tile[cl][col] = feat[((size_t)(b * 256 + c0 + cl) << 12) + sp0 + col];
    }
    __syncthreads();
    #pragma unroll
    for (int u = 0; u < 4; ++u) {
        int spl = rowg + u * 8;
        X[(size_t)(b * 4096 + sp0 + spl) * 256 + c0 + col] = __float2bfloat16(tile[col][spl]);
    }
}

// ---------------- prep: cast weights to bf16 into wbf ----------------
__global__ __launch_bounds__(256) void cast_weights(const float* __restrict__ in_w,
                                                    const float* __restrict__ out_w,
                                                    const float* __restrict__ proj_w,
                                                    __hip_bfloat16* __restrict__ wbf) {
    const int i = blockIdx.x * 256 + threadIdx.x;   // grid covers 262144
    if (i < 196608) wbf[i] = __float2bfloat16(in_w[i]);
    if (i < 65536)  wbf[196608 + i] = __float2bfloat16(out_w[i]);
    if (i < 262144) wbf[262144 + i] = __float2bfloat16(proj_w[i]);
}

// ---------------- MFMA GEMM: C[M][Ntot] = A[M][KDIM] @ W[Ntot][KDIM]^T + bias ----------------
// 128x128 tile, BK=32, 4 waves (2x2) each 64x64 via 4x4 frags of 16x16x32.
// Verified layouts (m89/m92): A/B frag = 8 contiguous k at row (lane&15), k0=(lane>>4)*8;
// C/D: col = lane&15, row = (lane>>4)*4 + reg.
template <int KDIM, bool OUT_BF16>
__global__ __launch_bounds__(256) void mfma_gemm(const __hip_bfloat16* __restrict__ A,
                                                 const __hip_bfloat16* __restrict__ W,
                                                 const float* __restrict__ bias,
                                                 void* __restrict__ C, int Ntot) {
    __shared__ __align__(16) short As[128][40];  // stride 40 shorts = 80 B: 2-way max on b128 reads
    __shared__ __align__(16) short Bs[128][40];
    const int tid = threadIdx.x;
    const int m0 = blockIdx.x * 128;
    const int n0 = blockIdx.y * 128;
    const int wave = tid >> 6, lane = tid & 63;
    const int wm = (wave >> 1) * 64;
    const int wn = (wave & 1) * 64;
    const int fm = lane & 15;
    const int fq = lane >> 4;

    f32x4 acc[4][4] = {};

    for (int k0 = 0; k0 < KDIM; k0 += 32) {
        #pragma unroll
        for (int u = 0; u < 2; ++u) {
            const int idx = tid + u * 256;       // 0..511
            const int r = idx >> 2;              // 0..127
            const int c = (idx & 3) * 8;         // {0,8,16,24}
            *(int4*)(&As[r][c]) = *(const int4*)(A + (size_t)(m0 + r) * KDIM + k0 + c);
            *(int4*)(&Bs[r][c]) = *(const int4*)(W + (size_t)(n0 + r) * KDIM + k0 + c);
        }
        __syncthreads();
        bf16x8 af[4], bw[4];
        #pragma unroll
        for (int i = 0; i < 4; ++i)
            af[i] = *(const bf16x8*)(&As[wm + i * 16 + fm][fq * 8]);
        #pragma unroll
        for (int j = 0; j < 4; ++j)
            bw[j] = *(const bf16x8*)(&Bs[wn + j * 16 + fm][fq * 8]);
        #pragma unroll
        for (int i = 0; i < 4; ++i)
            #pragma unroll
            for (int j = 0; j < 4; ++j)
                acc[i][j] = __builtin_amdgcn_mfma_f32_16x16x32_bf16(af[i], bw[j], acc[i][j], 0, 0, 0);
        __syncthreads();
    }
    #pragma unroll
    for (int j = 0; j < 4; ++j) {
        const int col = n0 + wn + j * 16 + fm;
        const float bv = bias[col];
        #pragma unroll
        for (int i = 0; i < 4; ++i) {
            #pragma unroll
            for (int r = 0; r < 4; ++r) {
                const int row = m0 + wm + i * 16 + fq * 4 + r;
                const float v = acc[i][j][r] + bv;
                if (OUT_BF16)
                    ((__hip_bfloat16*)C)[(size_t)row * Ntot + col] = __float2bfloat16(v);
                else
                    ((float*)C)[(size_t)row * Ntot + col] = v;
            }
        }
    }
}

// ---------------- sparse masked attention (bf16 qkv), one wave per (token, head) ----------------
__global__ __launch_bounds__(256) void attn_kernel(const __hip_bfloat16* __restrict__ qkv,
                                                   __hip_bfloat16* __restrict__ ctx) {
    const int w = blockIdx.x * 4 + (threadIdx.x >> 6);
    const int lane = threadIdx.x & 63;
    const int head = w & 3;
    const int x = (w >> 2) & 31;
    const int y = (w >> 7) & 63;
    const int b = (w >> 13) & 7;
    const int side = (w >> 16) & 1;
    const int xq = side ? (32 + x) : x;
    const int tq = (b << 12) + (y << 6) + xq;

    const float qv = __bfloat162float(qkv[(size_t)tq * 768 + (head << 6) + lane]);

    const int dyv[13] = {0, 0, 0, 0, 0, -1, -1, -1, 1, 1, 1, -2, 2};
    const int dxv[13] = {0, -1, 1, -2, 2, 0, -1, 1, 0, -1, 1, 0, 0};

    float sc[13];
    float m = -1e30f;
    #pragma unroll
    for (int i = 0; i < 13; ++i) {
        const int yy = y + dyv[i], xx = x + dxv[i];
        const bool ok = (yy >= 0 && yy < 64 && xx >= 0 && xx < 32);  // wave-uniform
        float s = -1e30f;
        if (ok) {
            const int xm = side ? (31 - xx) : (63 - xx);
            const int tm = (b << 12) + (yy << 6) + xm;
            float p = qv * __bfloat162float(qkv[(size_t)tm * 768 + 256 + (head << 6) + lane]);
            #pragma unroll
            for (int o = 1; o < 64; o <<= 1) p += __shfl_xor(p, o, 64);
            s = p * 0.125f;  // 1/sqrt(64)
        }
        sc[i] = s;
        m = fmaxf(m, s);
    }
    float l = 0.f, acc = 0.f;
    #pragma unroll
    for (int i = 0; i < 13; ++i) {
        const int yy = y + dyv[i], xx = x + dxv[i];
        const bool ok = (yy >= 0 && yy < 64 && xx >= 0 && xx < 32);
        if (ok) {
            const float p = __expf(sc[i] - m);
            l += p;
            const int xm = side ? (31 - xx) : (63 - xx);
            const int tm = (b << 12) + (yy << 6) + xm;
            acc += p * __bfloat162float(qkv[(size_t)tm * 768 + 512 + (head << 6) + lane]);
        }
    }
    ctx[(size_t)tq * 256 + (head << 6) + lane] = __float2bfloat16(acc / l);
}

// ---------------- asym[t] = [q, c, |q-c|, q*c] in bf16 ----------------
__global__ __launch_bounds__(256) void build_asym(const __hip_bfloat16* __restrict__ X,
                                                  const __hip_bfloat16* __restrict__ c2,
                                                  __hip_bfloat16* __restrict__ asym) {
    const int t = blockIdx.x;
    const int c = threadIdx.x;
    const float q  = __bfloat162float(X[(size_t)t * 256 + c]);
    const float cx = __bfloat162float(c2[(size_t)t * 256 + c]);
    const size_t base = (size_t)t * 1024;
    asym[base + c]       = __float2bfloat16(q);
    asym[base + 256 + c] = __float2bfloat16(cx);
    asym[base + 512 + c] = __float2bfloat16(fabsf(q - cx));
    asym[base + 768 + c] = __float2bfloat16(q * cx);
}

// ---------------- LN + ReLU + transposed store ----------------
__global__ __launch_bounds__(256) void ln_relu_store(const float* __restrict__ y,
                                                     const float* __restrict__ ln_g,
                                                     const float* __restrict__ ln_b,
                                                     float* __restrict__ out) {
    __shared__ float ys[32][257];
    __shared__ float mu_s[32], inv_s[32];
    const int tid = threadIdx.x;
    const int t0 = blockIdx.x * 32;
    const int b = t0 >> 12, sp = t0 & 4095;
    #pragma unroll
    for (int u = 0; u < 32; ++u) {
        const int idx = tid + u * 256;
        ys[idx >> 8][idx & 255] = y[(size_t)(t0 + (idx >> 8)) * 256 + (idx & 255)];
    }
    __syncthreads();
    {
        const int tt = tid >> 3, seg = tid & 7;
        float s = 0.f, ss = 0.f;
        #pragma unroll
        for (int j = 0; j < 32; ++j) {
            const float v = ys[tt][seg * 32 + j];
            s += v; ss += v * v;
        }
        #pragma unroll
        for (int o = 1; o < 8; o <<= 1) {
            s += __shfl_xor(s, o, 8);
            ss += __shfl_xor(ss, o, 8);
        }
        if (seg == 0) {
            const float mu = s * (1.f / 256.f);
            const float var = ss * (1.f / 256.f) - mu * mu;
            mu_s[tt] = mu;
            inv_s[tt] = rsqrtf(var + 1e-5f);
        }
    }
    __syncthreads();
    const int tl = tid & 31, j0 = tid >> 5;
    const float mu = mu_s[tl], inv = inv_s[tl];
    #pragma unroll
    for (int u = 0; u < 32; ++u) {
        const int j = j0 + u * 8;
        const float v = (ys[tl][j] - mu) * inv * ln_g[j] + ln_b[j];
        out[((size_t)(b * 256 + j) << 12) + sp + tl] = fmaxf(v, 0.f);
    }
}

extern "C" void kernel_launch(void* const* d_in, const int* in_sizes, int n_in,
                              void* d_out, int out_size, void* d_ws, size_t ws_size,
                              hipStream_t stream) {
    (void)in_sizes; (void)n_in; (void)out_size; (void)ws_size;
    const float* feat   = (const float*)d_in[0];
    const float* in_w   = (const float*)d_in[1];
    const float* in_b   = (const float*)d_in[2];
    const float* out_w  = (const float*)d_in[3];
    const float* out_b  = (const float*)d_in[4];
    const float* proj_w = (const float*)d_in[5];
    const float* proj_b = (const float*)d_in[6];
    const float* ln_g   = (const float*)d_in[7];
    const float* ln_b   = (const float*)d_in[8];
    float* out = (float*)d_out;

    char* ws = (char*)d_ws;
    __hip_bfloat16* Xbf  = (__hip_bfloat16*)(ws);
    __hip_bfloat16* wbf  = (__hip_bfloat16*)(ws + (size_t)(16) * (1 << 20));
    __hip_bfloat16* qkv  = (__hip_bfloat16*)(ws + (size_t)(17) * (1 << 20));
    __hip_bfloat16* ctx  = (__hip_bfloat16*)(ws + (size_t)(65) * (1 << 20));
    __hip_bfloat16* asym = (__hip_bfloat16*)(ws + (size_t)(17) * (1 << 20));
    __hip_bfloat16* ctx2 = (__hip_bfloat16*)(ws + (size_t)(81) * (1 << 20));
    float*          yb   = (float*)         (ws + (size_t)(81) * (1 << 20));
    __hip_bfloat16* in_wbf   = wbf;
    __hip_bfloat16* out_wbf  = wbf + 196608;
    __hip_bfloat16* proj_wbf = wbf + 262144;

    transpose_cast<<<dim3(128, 8, 8), 256, 0, stream>>>(feat, Xbf);
    cast_weights  <<<1024, 256, 0, stream>>>(in_w, out_w, proj_w, wbf);
    mfma_gemm<256, true><<<dim3(256, 6), 256, 0, stream>>>(Xbf, in_wbf, in_b, qkv, 768);
    attn_kernel   <<<NTOK, 256, 0, stream>>>(qkv, ctx);
    mfma_gemm<256, true><<<dim3(256, 2), 256, 0, stream>>>(ctx, out_wbf, out_b, ctx2, 256);
    build_asym    <<<NTOK, 256, 0, stream>>>(Xbf, ctx2, asym);
    mfma_gemm<1024, false><<<dim3(256, 2), 256, 0, stream>>>(asym, proj_wbf, proj_b, yb, 256);
    ln_relu_store <<<NTOK / 32, 256, 0, stream>>>(yb, ln_g, ln_b, out);
}

// Round 4
// 251.444 us; speedup vs baseline: 6.4293x; 1.4794x over previous
//
#include <hip/hip_runtime.h>
#include <hip/hip_bf16.h>

// ContralateralAttention, bf16-MFMA version, round 3.
// Tokens: t = b*4096 + y*64 + x (x in [0,64)), 32768 total.
// ws layout (MB = 1<<20), lifetime-packed, peak 97 MB:
//   Xbf   [  0, 16)   32768x256  bf16 token-major feat
//   wbf   [ 16, 17)   in_w(196608) | out_w(65536) | proj_w(262144) bf16
//   qkv   [ 17, 65)   32768x768  bf16            (dead after attn)
//   y     [ 17, 49)   32768x256  f32   (aliases dead qkv)
//   ctx   [ 65, 81)   32768x256  bf16            (dead after outproj)
//   ctx2  [ 81, 97)   32768x256  bf16            (dead after proj gemm)

#define NTOK 32768

using bf16x8 = __attribute__((ext_vector_type(8))) short;
using f32x4  = __attribute__((ext_vector_type(4))) float;

__device__ __forceinline__ float b2f(short s) {
    unsigned u = ((unsigned)(unsigned short)s) << 16;
    union { unsigned u; float f; } c; c.u = u; return c.f;
}
__device__ __forceinline__ short f2b(float f) {
    __hip_bfloat16 h = __float2bfloat16(f);
    return *(short*)&h;
}

// ---------------- prep: feat (b,c,sp) f32 -> Xbf (t, c) bf16 ----------------
__global__ __launch_bounds__(256) void transpose_cast(const float* __restrict__ feat,
                                                      __hip_bfloat16* __restrict__ X) {
    __shared__ float tile[32][33];
    const int b  = blockIdx.z;
    const int c0 = blockIdx.y * 32;
    const int sp0 = blockIdx.x * 32;
    const int tid = threadIdx.x;
    const int col = tid & 31, rowg = tid >> 5;
    #pragma unroll
    for (int u = 0; u < 4; ++u) {
        int cl = rowg + u * 8;
        tile[cl][col] = feat[((size_t)(b * 256 + c0 + cl) << 12) + sp0 + col];
    }
    __syncthreads();
    #pragma unroll
    for (int u = 0; u < 4; ++u) {
        int spl = rowg + u * 8;
        X[(size_t)(b * 4096 + sp0 + spl) * 256 + c0 + col] = __float2bfloat16(tile[col][spl]);
    }
}

// ---------------- prep: cast weights to bf16 ----------------
__global__ __launch_bounds__(256) void cast_weights(const float* __restrict__ in_w,
                                                    const float* __restrict__ out_w,
                                                    const float* __restrict__ proj_w,
                                                    __hip_bfloat16* __restrict__ wbf) {
    const int i = blockIdx.x * 256 + threadIdx.x;
    if (i < 196608) wbf[i] = __float2bfloat16(in_w[i]);
    if (i < 65536)  wbf[196608 + i] = __float2bfloat16(out_w[i]);
    if (i < 262144) wbf[262144 + i] = __float2bfloat16(proj_w[i]);
}

// ---------------- MFMA GEMM (qkv / outproj): C = A[M][KDIM] @ W[N][KDIM]^T + bias ----------------
template <int KDIM, bool OUT_BF16>
__global__ __launch_bounds__(256) void mfma_gemm(const __hip_bfloat16* __restrict__ A,
                                                 const __hip_bfloat16* __restrict__ W,
                                                 const float* __restrict__ bias,
                                                 void* __restrict__ C, int Ntot) {
    __shared__ __align__(16) short As[128][40];
    __shared__ __align__(16) short Bs[128][40];
    const int tid = threadIdx.x;
    const int m0 = blockIdx.x * 128;
    const int n0 = blockIdx.y * 128;
    const int wave = tid >> 6, lane = tid & 63;
    const int wm = (wave >> 1) * 64;
    const int wn = (wave & 1) * 64;
    const int fm = lane & 15;
    const int fq = lane >> 4;

    f32x4 acc[4][4] = {};

    for (int k0 = 0; k0 < KDIM; k0 += 32) {
        #pragma unroll
        for (int u = 0; u < 2; ++u) {
            const int idx = tid + u * 256;
            const int r = idx >> 2;
            const int c = (idx & 3) * 8;
            *(int4*)(&As[r][c]) = *(const int4*)(A + (size_t)(m0 + r) * KDIM + k0 + c);
            *(int4*)(&Bs[r][c]) = *(const int4*)(W + (size_t)(n0 + r) * KDIM + k0 + c);
        }
        __syncthreads();
        bf16x8 af[4], bw[4];
        #pragma unroll
        for (int i = 0; i < 4; ++i)
            af[i] = *(const bf16x8*)(&As[wm + i * 16 + fm][fq * 8]);
        #pragma unroll
        for (int j = 0; j < 4; ++j)
            bw[j] = *(const bf16x8*)(&Bs[wn + j * 16 + fm][fq * 8]);
        #pragma unroll
        for (int i = 0; i < 4; ++i)
            #pragma unroll
            for (int j = 0; j < 4; ++j)
                acc[i][j] = __builtin_amdgcn_mfma_f32_16x16x32_bf16(af[i], bw[j], acc[i][j], 0, 0, 0);
        __syncthreads();
    }
    #pragma unroll
    for (int j = 0; j < 4; ++j) {
        const int col = n0 + wn + j * 16 + fm;
        const float bv = bias[col];
        #pragma unroll
        for (int i = 0; i < 4; ++i) {
            #pragma unroll
            for (int r = 0; r < 4; ++r) {
                const int row = m0 + wm + i * 16 + fq * 4 + r;
                const float v = acc[i][j][r] + bv;
                if (OUT_BF16)
                    ((__hip_bfloat16*)C)[(size_t)row * Ntot + col] = __float2bfloat16(v);
                else
                    ((float*)C)[(size_t)row * Ntot + col] = v;
            }
        }
    }
}

// ---------------- sparse attention: lanes = 8 neighbors x 8 channel-octets ----------------
// pass0 neighbors: (0,0),(0,-1),(0,1),(0,-2),(0,2),(-1,0),(-1,-1),(-1,1)
// pass1 neighbors: (1,0),(1,-1),(1,1),(-2,0),(2,0)   [slots 5..7 invalid]
#define P0DY ((2u)|(2u<<3)|(2u<<6)|(2u<<9)|(2u<<12)|(1u<<15)|(1u<<18)|(1u<<21))
#define P0DX ((2u)|(1u<<3)|(3u<<6)|(0u<<9)|(4u<<12)|(2u<<15)|(1u<<18)|(3u<<21))
#define P1DY ((3u)|(3u<<3)|(3u<<6)|(0u<<9)|(4u<<12)|(2u<<15)|(2u<<18)|(2u<<21))
#define P1DX ((2u)|(1u<<3)|(3u<<6)|(2u<<9)|(2u<<12)|(2u<<15)|(2u<<18)|(2u<<21))

__global__ __launch_bounds__(256) void attn_kernel(const __hip_bfloat16* __restrict__ qkv,
                                                   __hip_bfloat16* __restrict__ ctx) {
    const int w = blockIdx.x * 4 + (threadIdx.x >> 6);
    const int lane = threadIdx.x & 63;
    const int n  = lane >> 3;     // neighbor slot
    const int cg = lane & 7;      // channel octet
    const int head = w & 3;
    const int x = (w >> 2) & 31;
    const int y = (w >> 7) & 63;
    const int b = (w >> 13) & 7;
    const int side = (w >> 16) & 1;
    const int xq = side ? (32 + x) : x;
    const int tq = (b << 12) + (y << 6) + xq;

    // q octet (same address across the 8 neighbor-slots -> broadcast)
    float qf[8];
    {
        bf16x8 q8 = *(const bf16x8*)(qkv + (size_t)tq * 768 + (head << 6) + cg * 8);
        #pragma unroll
        for (int j = 0; j < 8; ++j) qf[j] = b2f(q8[j]);
    }

    float sc[2];
    float vf[2][8];
    #pragma unroll
    for (int p = 0; p < 2; ++p) {
        const unsigned dyp = p ? P1DY : P0DY;
        const unsigned dxp = p ? P1DX : P0DX;
        const int sh = 3 * n;
        const int dy = (int)((dyp >> sh) & 7) - 2;
        const int dx = (int)((dxp >> sh) & 7) - 2;
        const int yy = y + dy, xx = x + dx;
        const bool valid = (p == 0 || n < 5) && yy >= 0 && yy < 64 && xx >= 0 && xx < 32;
        const int xm = side ? (31 - xx) : (63 - xx);
        int tm = (b << 12) + (yy << 6) + xm;
        if (!valid) tm = tq;  // keep address in bounds
        const size_t kb = (size_t)tm * 768 + 256 + (head << 6) + cg * 8;
        bf16x8 k8 = *(const bf16x8*)(qkv + kb);
        bf16x8 v8 = *(const bf16x8*)(qkv + kb + 256);
        float s = 0.f;
        #pragma unroll
        for (int j = 0; j < 8; ++j) s += qf[j] * b2f(k8[j]);
        s += __shfl_xor(s, 1, 64);
        s += __shfl_xor(s, 2, 64);
        s += __shfl_xor(s, 4, 64);
        sc[p] = valid ? s * 0.125f : -1e30f;
        #pragma unroll
        for (int j = 0; j < 8; ++j) vf[p][j] = valid ? b2f(v8[j]) : 0.f;
    }

    float mx = fmaxf(sc[0], sc[1]);
    mx = fmaxf(mx, __shfl_xor(mx, 8, 64));
    mx = fmaxf(mx, __shfl_xor(mx, 16, 64));
    mx = fmaxf(mx, __shfl_xor(mx, 32, 64));
    const float p0 = __expf(sc[0] - mx);
    const float p1 = __expf(sc[1] - mx);
    float l = p0 + p1;
    l += __shfl_xor(l, 8, 64);
    l += __shfl_xor(l, 16, 64);
    l += __shfl_xor(l, 32, 64);

    float o8[8];
    #pragma unroll
    for (int j = 0; j < 8; ++j) o8[j] = p0 * vf[0][j] + p1 * vf[1][j];
    #pragma unroll
    for (int j = 0; j < 8; ++j) {
        o8[j] += __shfl_xor(o8[j], 8, 64);
        o8[j] += __shfl_xor(o8[j], 16, 64);
        o8[j] += __shfl_xor(o8[j], 32, 64);
    }
    if (n == 0) {
        const float rl = 1.f / l;
        bf16x8 r;
        #pragma unroll
        for (int j = 0; j < 8; ++j) r[j] = f2b(o8[j] * rl);
        *(bf16x8*)(ctx + (size_t)tq * 256 + (head << 6) + cg * 8) = r;
    }
}

// ---------------- fused proj GEMM: A = [q | c | |q-c| | q*c] on the fly, K=1024 ----------------
__global__ __launch_bounds__(256) void proj_gemm_fused(const __hip_bfloat16* __restrict__ X,
                                                       const __hip_bfloat16* __restrict__ C2,
                                                       const __hip_bfloat16* __restrict__ W,
                                                       const float* __restrict__ bias,
                                                       float* __restrict__ Y) {
    __shared__ __align__(16) short As[128][40];
    __shared__ __align__(16) short Bs[128][40];
    const int tid = threadIdx.x;
    const int m0 = blockIdx.x * 128;
    const int n0 = blockIdx.y * 128;
    const int wave = tid >> 6, lane = tid & 63;
    const int wm = (wave >> 1) * 64;
    const int wn = (wave & 1) * 64;
    const int fm = lane & 15;
    const int fq = lane >> 4;

    f32x4 acc[4][4] = {};

    for (int k0 = 0; k0 < 1024; k0 += 32) {
        const int g = k0 >> 8;        // wave-uniform group
        const int cb = k0 & 255;
        #pragma unroll
        for (int u = 0; u < 2; ++u) {
            const int idx = tid + u * 256;
            const int r = idx >> 2;
            const int c = (idx & 3) * 8;
            const size_t abase = (size_t)(m0 + r) * 256 + cb + c;
            int4 outv;
            if (g == 0) {
                outv = *(const int4*)(X + abase);
            } else if (g == 1) {
                outv = *(const int4*)(C2 + abase);
            } else {
                int4 qraw = *(const int4*)(X + abase);
                int4 craw = *(const int4*)(C2 + abase);
                const short* qs = (const short*)&qraw;
                const short* cs = (const short*)&craw;
                short tmp[8];
                #pragma unroll
                for (int j = 0; j < 8; ++j) {
                    const float qv = b2f(qs[j]), cv = b2f(cs[j]);
                    tmp[j] = f2b(g == 2 ? fabsf(qv - cv) : qv * cv);
                }
                outv = *(int4*)tmp;
            }
            *(int4*)(&As[r][c]) = outv;
            *(int4*)(&Bs[r][c]) = *(const int4*)(W + (size_t)(n0 + r) * 1024 + k0 + c);
        }
        __syncthreads();
        bf16x8 af[4], bw[4];
        #pragma unroll
        for (int i = 0; i < 4; ++i)
            af[i] = *(const bf16x8*)(&As[wm + i * 16 + fm][fq * 8]);
        #pragma unroll
        for (int j = 0; j < 4; ++j)
            bw[j] = *(const bf16x8*)(&Bs[wn + j * 16 + fm][fq * 8]);
        #pragma unroll
        for (int i = 0; i < 4; ++i)
            #pragma unroll
            for (int j = 0; j < 4; ++j)
                acc[i][j] = __builtin_amdgcn_mfma_f32_16x16x32_bf16(af[i], bw[j], acc[i][j], 0, 0, 0);
        __syncthreads();
    }
    #pragma unroll
    for (int j = 0; j < 4; ++j) {
        const int col = n0 + wn + j * 16 + fm;
        const float bv = bias[col];
        #pragma unroll
        for (int i = 0; i < 4; ++i) {
            #pragma unroll
            for (int r = 0; r < 4; ++r) {
                const int row = m0 + wm + i * 16 + fq * 4 + r;
                Y[(size_t)row * 256 + col] = acc[i][j][r] + bv;
            }
        }
    }
}

// ---------------- LN + ReLU + transposed store ----------------
__global__ __launch_bounds__(256) void ln_relu_store(const float* __restrict__ y,
                                                     const float* __restrict__ ln_g,
                                                     const float* __restrict__ ln_b,
                                                     float* __restrict__ out) {
    __shared__ float ys[32][257];
    __shared__ float mu_s[32], inv_s[32];
    const int tid = threadIdx.x;
    const int t0 = blockIdx.x * 32;
    const int b = t0 >> 12, sp = t0 & 4095;
    #pragma unroll
    for (int u = 0; u < 32; ++u) {
        const int idx = tid + u * 256;
        ys[idx >> 8][idx & 255] = y[(size_t)(t0 + (idx >> 8)) * 256 + (idx & 255)];
    }
    __syncthreads();
    {
        const int tt = tid >> 3, seg = tid & 7;
        float s = 0.f, ss = 0.f;
        #pragma unroll
        for (int j = 0; j < 32; ++j) {
            const float v = ys[tt][seg * 32 + j];
            s += v; ss += v * v;
        }
        #pragma unroll
        for (int o = 1; o < 8; o <<= 1) {
            s += __shfl_xor(s, o, 8);
            ss += __shfl_xor(ss, o, 8);
        }
        if (seg == 0) {
            const float mu = s * (1.f / 256.f);
            const float var = ss * (1.f / 256.f) - mu * mu;
            mu_s[tt] = mu;
            inv_s[tt] = rsqrtf(var + 1e-5f);
        }
    }
    __syncthreads();
    const int tl = tid & 31, j0 = tid >> 5;
    const float mu = mu_s[tl], inv = inv_s[tl];
    #pragma unroll
    for (int u = 0; u < 32; ++u) {
        const int j = j0 + u * 8;
        const float v = (ys[tl][j] - mu) * inv * ln_g[j] + ln_b[j];
        out[((size_t)(b * 256 + j) << 12) + sp + tl] = fmaxf(v, 0.f);
    }
}

extern "C" void kernel_launch(void* const* d_in, const int* in_sizes, int n_in,
                              void* d_out, int out_size, void* d_ws, size_t ws_size,
                              hipStream_t stream) {
    (void)in_sizes; (void)n_in; (void)out_size; (void)ws_size;
    const float* feat   = (const float*)d_in[0];
    const float* in_w   = (const float*)d_in[1];
    const float* in_b   = (const float*)d_in[2];
    const float* out_w  = (const float*)d_in[3];
    const float* out_b  = (const float*)d_in[4];
    const float* proj_w = (const float*)d_in[5];
    const float* proj_b = (const float*)d_in[6];
    const float* ln_g   = (const float*)d_in[7];
    const float* ln_b   = (const float*)d_in[8];
    float* out = (float*)d_out;

    char* ws = (char*)d_ws;
    __hip_bfloat16* Xbf  = (__hip_bfloat16*)(ws);
    __hip_bfloat16* wbf  = (__hip_bfloat16*)(ws + (size_t)(16) * (1 << 20));
    __hip_bfloat16* qkv  = (__hip_bfloat16*)(ws + (size_t)(17) * (1 << 20));
    float*          yb   = (float*)         (ws + (size_t)(17) * (1 << 20)); // aliases dead qkv
    __hip_bfloat16* ctx  = (__hip_bfloat16*)(ws + (size_t)(65) * (1 << 20));
    __hip_bfloat16* ctx2 = (__hip_bfloat16*)(ws + (size_t)(81) * (1 << 20));
    __hip_bfloat16* in_wbf   = wbf;
    __hip_bfloat16* out_wbf  = wbf + 196608;
    __hip_bfloat16* proj_wbf = wbf + 262144;

    transpose_cast<<<dim3(128, 8, 8), 256, 0, stream>>>(feat, Xbf);
    cast_weights  <<<1024, 256, 0, stream>>>(in_w, out_w, proj_w, wbf);
    mfma_gemm<256, true><<<dim3(256, 6), 256, 0, stream>>>(Xbf, in_wbf, in_b, qkv, 768);
    attn_kernel   <<<NTOK, 256, 0, stream>>>(qkv, ctx);
    mfma_gemm<256, true><<<dim3(256, 2), 256, 0, stream>>>(ctx, out_wbf, out_b, ctx2, 256);
    proj_gemm_fused<<<dim3(256, 2), 256, 0, stream>>>(Xbf, ctx2, proj_wbf, proj_b, yb);
    ln_relu_store <<<NTOK / 32, 256, 0, stream>>>(yb, ln_g, ln_b, out);
}

// Round 5
// 233.719 us; speedup vs baseline: 6.9169x; 1.0758x over previous
//
#include <hip/hip_runtime.h>
#include <hip/hip_bf16.h>

// ContralateralAttention, bf16-MFMA + global_load_lds staging, round 4.
// Tokens: t = b*4096 + y*64 + x (x in [0,64)), 32768 total.
// ws layout (MB), lifetime-packed, peak 97 MB:
//   Xbf   [  0, 16)   32768x256  bf16
//   wbf   [ 16, 17)   in_w | out_w | proj_w bf16
//   qkv   [ 17, 65)   32768x768  bf16   (dead after attn)
//   y     [ 17, 49)   32768x256  f32    (aliases dead qkv)
//   ctx   [ 65, 81)   32768x256  bf16
//   ctx2  [ 81, 97)   32768x256  bf16

#define NTOK 32768

using bf16x8 = __attribute__((ext_vector_type(8))) short;
using f32x4  = __attribute__((ext_vector_type(4))) float;

__device__ __forceinline__ float b2f(short s) {
    unsigned u = ((unsigned)(unsigned short)s) << 16;
    union { unsigned u; float f; } c; c.u = u; return c.f;
}
__device__ __forceinline__ short f2b(float f) {
    __hip_bfloat16 h = __float2bfloat16(f);
    return *(short*)&h;
}
// async 16B global->LDS. LDS dest = (uniform) l + lane*16.
__device__ __forceinline__ void async_copy16(const void* g, void* l) {
    __builtin_amdgcn_global_load_lds(
        (const __attribute__((address_space(1))) unsigned int*)g,
        (__attribute__((address_space(3))) unsigned int*)l, 16, 0, 0);
}
// chunk-column swizzle so DMA'd (unpadded) tiles read conflict-free
__device__ __forceinline__ int swz(int r) { return (r ^ (r >> 2)) & 3; }

// ---------------- prep: feat (b,c,sp) f32 -> Xbf (t, c) bf16 ----------------
__global__ __launch_bounds__(256) void transpose_cast(const float* __restrict__ feat,
                                                      __hip_bfloat16* __restrict__ X) {
    __shared__ float tile[32][33];
    const int b  = blockIdx.z;
    const int c0 = blockIdx.y * 32;
    const int sp0 = blockIdx.x * 32;
    const int tid = threadIdx.x;
    const int col = tid & 31, rowg = tid >> 5;
    #pragma unroll
    for (int u = 0; u < 4; ++u) {
        int cl = rowg + u * 8;
        tile[cl][col] = feat[((size_t)(b * 256 + c0 + cl) << 12) + sp0 + col];
    }
    __syncthreads();
    #pragma unroll
    for (int u = 0; u < 4; ++u) {
        int spl = rowg + u * 8;
        X[(size_t)(b * 4096 + sp0 + spl) * 256 + c0 + col] = __float2bfloat16(tile[col][spl]);
    }
}

// ---------------- prep: cast weights to bf16 ----------------
__global__ __launch_bounds__(256) void cast_weights(const float* __restrict__ in_w,
                                                    const float* __restrict__ out_w,
                                                    const float* __restrict__ proj_w,
                                                    __hip_bfloat16* __restrict__ wbf) {
    const int i = blockIdx.x * 256 + threadIdx.x;
    if (i < 196608) wbf[i] = __float2bfloat16(in_w[i]);
    if (i < 65536)  wbf[196608 + i] = __float2bfloat16(out_w[i]);
    if (i < 262144) wbf[262144 + i] = __float2bfloat16(proj_w[i]);
}

// ---------------- MFMA GEMM with global_load_lds staging ----------------
// C[M][Ntot] = A[M][KDIM] @ W[N][KDIM]^T + bias. 128x128 tile, BK=32.
// LDS tile: 128 rows x 32 shorts, unpadded; chunk (r,c) stored at slot r*4 + (c^swz(r)).
template <int KDIM, bool OUT_BF16>
__global__ __launch_bounds__(256) void mfma_gemm(const __hip_bfloat16* __restrict__ A,
                                                 const __hip_bfloat16* __restrict__ W,
                                                 const float* __restrict__ bias,
                                                 void* __restrict__ C, int Ntot) {
    __shared__ __align__(16) short As[128 * 32];
    __shared__ __align__(16) short Bs[128 * 32];
    const int tid = threadIdx.x;
    const int m0 = blockIdx.x * 128;
    const int n0 = blockIdx.y * 128;
    const int wave = tid >> 6, lane = tid & 63;
    const int wm = (wave >> 1) * 64;
    const int wn = (wave & 1) * 64;
    const int fm = lane & 15;
    const int fq = lane >> 4;
    const int cc = (fq ^ swz(fm)) * 8;   // lane-constant swizzled chunk offset (shorts)

    f32x4 acc[4][4] = {};

    for (int k0 = 0; k0 < KDIM; k0 += 32) {
        #pragma unroll
        for (int u = 0; u < 2; ++u) {
            const int qb = wave * 128 + u * 64;      // uniform chunk base
            const int q = qb + lane;
            const int r = q >> 2;
            const int cs = (q & 3) ^ swz(r);
            async_copy16(A + (size_t)(m0 + r) * KDIM + k0 + cs * 8, &As[qb * 8]);
            async_copy16(W + (size_t)(n0 + r) * KDIM + k0 + cs * 8, &Bs[qb * 8]);
        }
        __syncthreads();
        bf16x8 af[4], bw[4];
        #pragma unroll
        for (int i = 0; i < 4; ++i)
            af[i] = *(const bf16x8*)(&As[(wm + i * 16 + fm) * 32 + cc]);
        #pragma unroll
        for (int j = 0; j < 4; ++j)
            bw[j] = *(const bf16x8*)(&Bs[(wn + j * 16 + fm) * 32 + cc]);
        #pragma unroll
        for (int i = 0; i < 4; ++i)
            #pragma unroll
            for (int j = 0; j < 4; ++j)
                acc[i][j] = __builtin_amdgcn_mfma_f32_16x16x32_bf16(af[i], bw[j], acc[i][j], 0, 0, 0);
        __syncthreads();
    }
    #pragma unroll
    for (int j = 0; j < 4; ++j) {
        const int col = n0 + wn + j * 16 + fm;
        const float bv = bias[col];
        #pragma unroll
        for (int i = 0; i < 4; ++i) {
            #pragma unroll
            for (int r = 0; r < 4; ++r) {
                const int row = m0 + wm + i * 16 + fq * 4 + r;
                const float v = acc[i][j][r] + bv;
                if (OUT_BF16)
                    ((__hip_bfloat16*)C)[(size_t)row * Ntot + col] = __float2bfloat16(v);
                else
                    ((float*)C)[(size_t)row * Ntot + col] = v;
            }
        }
    }
}

// ---------------- sparse attention: lanes = 8 neighbors x 8 channel-octets ----------------
#define P0DY ((2u)|(2u<<3)|(2u<<6)|(2u<<9)|(2u<<12)|(1u<<15)|(1u<<18)|(1u<<21))
#define P0DX ((2u)|(1u<<3)|(3u<<6)|(0u<<9)|(4u<<12)|(2u<<15)|(1u<<18)|(3u<<21))
#define P1DY ((3u)|(3u<<3)|(3u<<6)|(0u<<9)|(4u<<12)|(2u<<15)|(2u<<18)|(2u<<21))
#define P1DX ((2u)|(1u<<3)|(3u<<6)|(2u<<9)|(2u<<12)|(2u<<15)|(2u<<18)|(2u<<21))

__global__ __launch_bounds__(256) void attn_kernel(const __hip_bfloat16* __restrict__ qkv,
                                                   __hip_bfloat16* __restrict__ ctx) {
    const int w = blockIdx.x * 4 + (threadIdx.x >> 6);
    const int lane = threadIdx.x & 63;
    const int n  = lane >> 3;
    const int cg = lane & 7;
    const int head = w & 3;
    const int x = (w >> 2) & 31;
    const int y = (w >> 7) & 63;
    const int b = (w >> 13) & 7;
    const int side = (w >> 16) & 1;
    const int xq = side ? (32 + x) : x;
    const int tq = (b << 12) + (y << 6) + xq;

    float qf[8];
    {
        bf16x8 q8 = *(const bf16x8*)(qkv + (size_t)tq * 768 + (head << 6) + cg * 8);
        #pragma unroll
        for (int j = 0; j < 8; ++j) qf[j] = b2f(q8[j]);
    }

    float sc[2];
    float vf[2][8];
    #pragma unroll
    for (int p = 0; p < 2; ++p) {
        const unsigned dyp = p ? P1DY : P0DY;
        const unsigned dxp = p ? P1DX : P0DX;
        const int sh = 3 * n;
        const int dy = (int)((dyp >> sh) & 7) - 2;
        const int dx = (int)((dxp >> sh) & 7) - 2;
        const int yy = y + dy, xx = x + dx;
        const bool valid = (p == 0 || n < 5) && yy >= 0 && yy < 64 && xx >= 0 && xx < 32;
        const int xm = side ? (31 - xx) : (63 - xx);
        int tm = (b << 12) + (yy << 6) + xm;
        if (!valid) tm = tq;
        const size_t kb = (size_t)tm * 768 + 256 + (head << 6) + cg * 8;
        bf16x8 k8 = *(const bf16x8*)(qkv + kb);
        bf16x8 v8 = *(const bf16x8*)(qkv + kb + 256);
        float s = 0.f;
        #pragma unroll
        for (int j = 0; j < 8; ++j) s += qf[j] * b2f(k8[j]);
        s += __shfl_xor(s, 1, 64);
        s += __shfl_xor(s, 2, 64);
        s += __shfl_xor(s, 4, 64);
        sc[p] = valid ? s * 0.125f : -1e30f;
        #pragma unroll
        for (int j = 0; j < 8; ++j) vf[p][j] = valid ? b2f(v8[j]) : 0.f;
    }

    float mx = fmaxf(sc[0], sc[1]);
    mx = fmaxf(mx, __shfl_xor(mx, 8, 64));
    mx = fmaxf(mx, __shfl_xor(mx, 16, 64));
    mx = fmaxf(mx, __shfl_xor(mx, 32, 64));
    const float p0 = __expf(sc[0] - mx);
    const float p1 = __expf(sc[1] - mx);
    float l = p0 + p1;
    l += __shfl_xor(l, 8, 64);
    l += __shfl_xor(l, 16, 64);
    l += __shfl_xor(l, 32, 64);

    float o8[8];
    #pragma unroll
    for (int j = 0; j < 8; ++j) o8[j] = p0 * vf[0][j] + p1 * vf[1][j];
    #pragma unroll
    for (int j = 0; j < 8; ++j) {
        o8[j] += __shfl_xor(o8[j], 8, 64);
        o8[j] += __shfl_xor(o8[j], 16, 64);
        o8[j] += __shfl_xor(o8[j], 32, 64);
    }
    if (n == 0) {
        const float rl = 1.f / l;
        bf16x8 r;
        #pragma unroll
        for (int j = 0; j < 8; ++j) r[j] = f2b(o8[j] * rl);
        *(bf16x8*)(ctx + (size_t)tq * 256 + (head << 6) + cg * 8) = r;
    }
}

// ---------------- fused proj GEMM: A = [q | c | |q-c| | q*c], K=1024 ----------------
__global__ __launch_bounds__(256) void proj_gemm_fused(const __hip_bfloat16* __restrict__ X,
                                                       const __hip_bfloat16* __restrict__ C2,
                                                       const __hip_bfloat16* __restrict__ W,
                                                       const float* __restrict__ bias,
                                                       float* __restrict__ Y) {
    __shared__ __align__(16) short As[128 * 32];
    __shared__ __align__(16) short Bs[128 * 32];
    const int tid = threadIdx.x;
    const int m0 = blockIdx.x * 128;
    const int n0 = blockIdx.y * 128;
    const int wave = tid >> 6, lane = tid & 63;
    const int wm = (wave >> 1) * 64;
    const int wn = (wave & 1) * 64;
    const int fm = lane & 15;
    const int fq = lane >> 4;
    const int cc = (fq ^ swz(fm)) * 8;

    f32x4 acc[4][4] = {};

    for (int k0 = 0; k0 < 1024; k0 += 32) {
        const int g = k0 >> 8;        // uniform group
        const int cb = k0 & 255;
        // B always via DMA
        #pragma unroll
        for (int u = 0; u < 2; ++u) {
            const int qb = wave * 128 + u * 64;
            const int q = qb + lane;
            const int r = q >> 2;
            const int cs = (q & 3) ^ swz(r);
            async_copy16(W + (size_t)(n0 + r) * 1024 + k0 + cs * 8, &Bs[qb * 8]);
        }
        if (g == 0) {
            #pragma unroll
            for (int u = 0; u < 2; ++u) {
                const int qb = wave * 128 + u * 64;
                const int q = qb + lane;
                const int r = q >> 2;
                const int cs = (q & 3) ^ swz(r);
                async_copy16(X + (size_t)(m0 + r) * 256 + cb + cs * 8, &As[qb * 8]);
            }
        } else if (g == 1) {
            #pragma unroll
            for (int u = 0; u < 2; ++u) {
                const int qb = wave * 128 + u * 64;
                const int q = qb + lane;
                const int r = q >> 2;
                const int cs = (q & 3) ^ swz(r);
                async_copy16(C2 + (size_t)(m0 + r) * 256 + cb + cs * 8, &As[qb * 8]);
            }
        } else {
            #pragma unroll
            for (int u = 0; u < 2; ++u) {
                const int q = tid + u * 256;
                const int r = q >> 2;
                const int cs = (q & 3) ^ swz(r);
                const size_t abase = (size_t)(m0 + r) * 256 + cb + cs * 8;
                int4 qraw = *(const int4*)(X + abase);
                int4 craw = *(const int4*)(C2 + abase);
                const short* qs = (const short*)&qraw;
                const short* cw = (const short*)&craw;
                short tmp[8];
                #pragma unroll
                for (int j = 0; j < 8; ++j) {
                    const float qv = b2f(qs[j]), cv = b2f(cw[j]);
                    tmp[j] = f2b(g == 2 ? fabsf(qv - cv) : qv * cv);
                }
                *(int4*)(&As[q * 8]) = *(int4*)tmp;
            }
        }
        __syncthreads();
        bf16x8 af[4], bw[4];
        #pragma unroll
        for (int i = 0; i < 4; ++i)
            af[i] = *(const bf16x8*)(&As[(wm + i * 16 + fm) * 32 + cc]);
        #pragma unroll
        for (int j = 0; j < 4; ++j)
            bw[j] = *(const bf16x8*)(&Bs[(wn + j * 16 + fm) * 32 + cc]);
        #pragma unroll
        for (int i = 0; i < 4; ++i)
            #pragma unroll
            for (int j = 0; j < 4; ++j)
                acc[i][j] = __builtin_amdgcn_mfma_f32_16x16x32_bf16(af[i], bw[j], acc[i][j], 0, 0, 0);
        __syncthreads();
    }
    #pragma unroll
    for (int j = 0; j < 4; ++j) {
        const int col = n0 + wn + j * 16 + fm;
        const float bv = bias[col];
        #pragma unroll
        for (int i = 0; i < 4; ++i) {
            #pragma unroll
            for (int r = 0; r < 4; ++r) {
                const int row = m0 + wm + i * 16 + fq * 4 + r;
                Y[(size_t)row * 256 + col] = acc[i][j][r] + bv;
            }
        }
    }
}

// ---------------- LN + ReLU + transposed store ----------------
__global__ __launch_bounds__(256) void ln_relu_store(const float* __restrict__ y,
                                                     const float* __restrict__ ln_g,
                                                     const float* __restrict__ ln_b,
                                                     float* __restrict__ out) {
    __shared__ float ys[32][257];
    __shared__ float mu_s[32], inv_s[32];
    const int tid = threadIdx.x;
    const int t0 = blockIdx.x * 32;
    const int b = t0 >> 12, sp = t0 & 4095;
    #pragma unroll
    for (int u = 0; u < 32; ++u) {
        const int idx = tid + u * 256;
        ys[idx >> 8][idx & 255] = y[(size_t)(t0 + (idx >> 8)) * 256 + (idx & 255)];
    }
    __syncthreads();
    {
        const int tt = tid >> 3, seg = tid & 7;
        float s = 0.f, ss = 0.f;
        #pragma unroll
        for (int j = 0; j < 32; ++j) {
            const float v = ys[tt][seg * 32 + j];
            s += v; ss += v * v;
        }
        #pragma unroll
        for (int o = 1; o < 8; o <<= 1) {
            s += __shfl_xor(s, o, 8);
            ss += __shfl_xor(ss, o, 8);
        }
        if (seg == 0) {
            const float mu = s * (1.f / 256.f);
            const float var = ss * (1.f / 256.f) - mu * mu;
            mu_s[tt] = mu;
            inv_s[tt] = rsqrtf(var + 1e-5f);
        }
    }
    __syncthreads();
    const int tl = tid & 31, j0 = tid >> 5;
    const float mu = mu_s[tl], inv = inv_s[tl];
    #pragma unroll
    for (int u = 0; u < 32; ++u) {
        const int j = j0 + u * 8;
        const float v = (ys[tl][j] - mu) * inv * ln_g[j] + ln_b[j];
        out[((size_t)(b * 256 + j) << 12) + sp + tl] = fmaxf(v, 0.f);
    }
}

extern "C" void kernel_launch(void* const* d_in, const int* in_sizes, int n_in,
                              void* d_out, int out_size, void* d_ws, size_t ws_size,
                              hipStream_t stream) {
    (void)in_sizes; (void)n_in; (void)out_size; (void)ws_size;
    const float* feat   = (const float*)d_in[0];
    const float* in_w   = (const float*)d_in[1];
    const float* in_b   = (const float*)d_in[2];
    const float* out_w  = (const float*)d_in[3];
    const float* out_b  = (const float*)d_in[4];
    const float* proj_w = (const float*)d_in[5];
    const float* proj_b = (const float*)d_in[6];
    const float* ln_g   = (const float*)d_in[7];
    const float* ln_b   = (const float*)d_in[8];
    float* out = (float*)d_out;

    char* ws = (char*)d_ws;
    __hip_bfloat16* Xbf  = (__hip_bfloat16*)(ws);
    __hip_bfloat16* wbf  = (__hip_bfloat16*)(ws + (size_t)(16) * (1 << 20));
    __hip_bfloat16* qkv  = (__hip_bfloat16*)(ws + (size_t)(17) * (1 << 20));
    float*          yb   = (float*)         (ws + (size_t)(17) * (1 << 20));
    __hip_bfloat16* ctx  = (__hip_bfloat16*)(ws + (size_t)(65) * (1 << 20));
    __hip_bfloat16* ctx2 = (__hip_bfloat16*)(ws + (size_t)(81) * (1 << 20));
    __hip_bfloat16* in_wbf   = wbf;
    __hip_bfloat16* out_wbf  = wbf + 196608;
    __hip_bfloat16* proj_wbf = wbf + 262144;

    transpose_cast<<<dim3(128, 8, 8), 256, 0, stream>>>(feat, Xbf);
    cast_weights  <<<1024, 256, 0, stream>>>(in_w, out_w, proj_w, wbf);
    mfma_gemm<256, true><<<dim3(256, 6), 256, 0, stream>>>(Xbf, in_wbf, in_b, qkv, 768);
    attn_kernel   <<<NTOK, 256, 0, stream>>>(qkv, ctx);
    mfma_gemm<256, true><<<dim3(256, 2), 256, 0, stream>>>(ctx, out_wbf, out_b, ctx2, 256);
    proj_gemm_fused<<<dim3(256, 2), 256, 0, stream>>>(Xbf, ctx2, proj_wbf, proj_b, yb);
    ln_relu_store <<<NTOK / 32, 256, 0, stream>>>(yb, ln_g, ln_b, out);
}

// Round 6
// 227.366 us; speedup vs baseline: 7.1102x; 1.0279x over previous
//
#include <hip/hip_runtime.h>
#include <hip/hip_bf16.h>

// ContralateralAttention, round 5: 4-head-fused attn, BK=64 DMA GEMMs, bf16 y.
// Tokens: t = b*4096 + y*64 + x (x in [0,64)), 32768 total.
// ws layout (MB), lifetime-packed:
//   Xbf   [  0, 16)   32768x256  bf16
//   wbf   [ 16, 17)   in_w | out_w | proj_w bf16
//   qkv   [ 17, 65)   32768x768  bf16   (dead after attn)
//   y     [ 17, 33)   32768x256  bf16   (aliases dead qkv)
//   ctx   [ 65, 81)   32768x256  bf16
//   ctx2  [ 81, 97)   32768x256  bf16

#define NTOK 32768

using bf16x8 = __attribute__((ext_vector_type(8))) short;
using f32x4  = __attribute__((ext_vector_type(4))) float;

__device__ __forceinline__ float b2f(short s) {
    unsigned u = ((unsigned)(unsigned short)s) << 16;
    union { unsigned u; float f; } c; c.u = u; return c.f;
}
__device__ __forceinline__ short f2b(float f) {
    __hip_bfloat16 h = __float2bfloat16(f);
    return *(short*)&h;
}
__device__ __forceinline__ void async_copy16(const void* g, void* l) {
    __builtin_amdgcn_global_load_lds(
        (const __attribute__((address_space(1))) unsigned int*)g,
        (__attribute__((address_space(3))) unsigned int*)l, 16, 0, 0);
}

// ---------------- prep: feat (b,c,sp) f32 -> Xbf (t, c) bf16 ----------------
__global__ __launch_bounds__(256) void transpose_cast(const float* __restrict__ feat,
                                                      __hip_bfloat16* __restrict__ X) {
    __shared__ float tile[32][33];
    const int b  = blockIdx.z;
    const int c0 = blockIdx.y * 32;
    const int sp0 = blockIdx.x * 32;
    const int tid = threadIdx.x;
    const int col = tid & 31, rowg = tid >> 5;
    #pragma unroll
    for (int u = 0; u < 4; ++u) {
        int cl = rowg + u * 8;
        tile[cl][col] = feat[((size_t)(b * 256 + c0 + cl) << 12) + sp0 + col];
    }
    __syncthreads();
    #pragma unroll
    for (int u = 0; u < 4; ++u) {
        int spl = rowg + u * 8;
        X[(size_t)(b * 4096 + sp0 + spl) * 256 + c0 + col] = __float2bfloat16(tile[col][spl]);
    }
}

// ---------------- prep: cast weights to bf16 ----------------
__global__ __launch_bounds__(256) void cast_weights(const float* __restrict__ in_w,
                                                    const float* __restrict__ out_w,
                                                    const float* __restrict__ proj_w,
                                                    __hip_bfloat16* __restrict__ wbf) {
    const int i = blockIdx.x * 256 + threadIdx.x;
    if (i < 196608) wbf[i] = __float2bfloat16(in_w[i]);
    if (i < 65536)  wbf[196608 + i] = __float2bfloat16(out_w[i]);
    if (i < 262144) wbf[262144 + i] = __float2bfloat16(proj_w[i]);
}

// ---------------- MFMA GEMM, BK=64, global_load_lds staging ----------------
// C[M][Ntot] = A[M][KDIM] @ W[N][KDIM]^T + bias. 128x128 tile.
// LDS tile 128 rows x 64 shorts; chunk (r,c) (c in [0,8), 16B chunks) at slot r*8 + (c ^ (r&7)).
// Read: lane fm,fq wants chunk col fq+4*kk -> slot col (fq+4*kk)^(fm&7): 2 rows/col = 2-way = free.
template <int KDIM, bool OUT_BF16>
__global__ __launch_bounds__(256) void mfma_gemm(const __hip_bfloat16* __restrict__ A,
                                                 const __hip_bfloat16* __restrict__ W,
                                                 const float* __restrict__ bias,
                                                 void* __restrict__ C, int Ntot) {
    __shared__ __align__(16) short As[128 * 64];
    __shared__ __align__(16) short Bs[128 * 64];
    const int tid = threadIdx.x;
    const int m0 = blockIdx.x * 128;
    const int n0 = blockIdx.y * 128;
    const int wave = tid >> 6, lane = tid & 63;
    const int wm = (wave >> 1) * 64;
    const int wn = (wave & 1) * 64;
    const int fm = lane & 15;
    const int fq = lane >> 4;

    f32x4 acc[4][4] = {};

    for (int k0 = 0; k0 < KDIM; k0 += 64) {
        #pragma unroll
        for (int v = 0; v < 4; ++v) {
            const int qb = v * 256 + wave * 64;       // uniform chunk base
            const int q = qb + lane;                  // 0..1023
            const int r = q >> 3;
            const int cs = (q & 7) ^ (r & 7);
            async_copy16(A + (size_t)(m0 + r) * KDIM + k0 + cs * 8, &As[qb * 8]);
            async_copy16(W + (size_t)(n0 + r) * KDIM + k0 + cs * 8, &Bs[qb * 8]);
        }
        __syncthreads();
        #pragma unroll
        for (int kk = 0; kk < 2; ++kk) {
            bf16x8 af[4], bw[4];
            #pragma unroll
            for (int i = 0; i < 4; ++i) {
                const int row = wm + i * 16 + fm;
                af[i] = *(const bf16x8*)(&As[row * 64 + (((fq + kk * 4) ^ (fm & 7)) * 8)]);
            }
            #pragma unroll
            for (int j = 0; j < 4; ++j) {
                const int row = wn + j * 16 + fm;
                bw[j] = *(const bf16x8*)(&Bs[row * 64 + (((fq + kk * 4) ^ (fm & 7)) * 8)]);
            }
            #pragma unroll
            for (int i = 0; i < 4; ++i)
                #pragma unroll
                for (int j = 0; j < 4; ++j)
                    acc[i][j] = __builtin_amdgcn_mfma_f32_16x16x32_bf16(af[i], bw[j], acc[i][j], 0, 0, 0);
        }
        __syncthreads();
    }
    #pragma unroll
    for (int j = 0; j < 4; ++j) {
        const int col = n0 + wn + j * 16 + fm;
        const float bv = bias[col];
        #pragma unroll
        for (int i = 0; i < 4; ++i) {
            #pragma unroll
            for (int r = 0; r < 4; ++r) {
                const int row = m0 + wm + i * 16 + fq * 4 + r;
                const float v = acc[i][j][r] + bv;
                if (OUT_BF16)
                    ((__hip_bfloat16*)C)[(size_t)row * Ntot + col] = __float2bfloat16(v);
                else
                    ((float*)C)[(size_t)row * Ntot + col] = v;
            }
        }
    }
}

// ---------------- sparse attention: one wave per token, 4 heads serial ----------------
// lanes = 8 neighbor-slots x 8 channel-octets.
// pass0: (0,0),(0,-1),(0,1),(0,-2),(0,2),(-1,0),(-1,-1),(-1,1)
// pass1: (1,0),(1,-1),(1,1),(-2,0),(2,0)  [slots 5..7 invalid]
#define P0DY ((2u)|(2u<<3)|(2u<<6)|(2u<<9)|(2u<<12)|(1u<<15)|(1u<<18)|(1u<<21))
#define P0DX ((2u)|(1u<<3)|(3u<<6)|(0u<<9)|(4u<<12)|(2u<<15)|(1u<<18)|(3u<<21))
#define P1DY ((3u)|(3u<<3)|(3u<<6)|(0u<<9)|(4u<<12)|(2u<<15)|(2u<<18)|(2u<<21))
#define P1DX ((2u)|(1u<<3)|(3u<<6)|(2u<<9)|(2u<<12)|(2u<<15)|(2u<<18)|(2u<<21))

__global__ __launch_bounds__(256) void attn_kernel(const __hip_bfloat16* __restrict__ qkv,
                                                   __hip_bfloat16* __restrict__ ctx) {
    const int t = blockIdx.x * 4 + (threadIdx.x >> 6);
    const int lane = threadIdx.x & 63;
    const int n  = lane >> 3;
    const int cg = lane & 7;
    const int x6 = t & 63;
    const int yq = (t >> 6) & 63;
    const int b  = t >> 12;
    const int side = x6 >> 5;
    const int x = x6 & 31;

    // neighbor geometry (head-invariant), computed once
    bool valid[2];
    size_t kb[2];
    #pragma unroll
    for (int p = 0; p < 2; ++p) {
        const unsigned dyp = p ? P1DY : P0DY;
        const unsigned dxp = p ? P1DX : P0DX;
        const int sh = 3 * n;
        const int dy = (int)((dyp >> sh) & 7) - 2;
        const int dx = (int)((dxp >> sh) & 7) - 2;
        const int yy = yq + dy, xx = x + dx;
        valid[p] = (p == 0 || n < 5) && yy >= 0 && yy < 64 && xx >= 0 && xx < 32;
        const int xm = side ? (31 - xx) : (63 - xx);
        int tm = (b << 12) + (yy << 6) + xm;
        if (!valid[p]) tm = t;  // in-bounds dummy; weight becomes 0 via softmax
        kb[p] = (size_t)tm * 768 + 256 + cg * 8;
    }
    const size_t qb = (size_t)t * 768 + cg * 8;
    const size_t ob = (size_t)t * 256 + cg * 8;

    #pragma unroll
    for (int h = 0; h < 4; ++h) {
        float qf[8];
        {
            bf16x8 q8 = *(const bf16x8*)(qkv + qb + h * 64);
            #pragma unroll
            for (int j = 0; j < 8; ++j) qf[j] = b2f(q8[j]);
        }
        float sc[2];
        float vf[2][8];
        #pragma unroll
        for (int p = 0; p < 2; ++p) {
            bf16x8 k8 = *(const bf16x8*)(qkv + kb[p] + h * 64);
            bf16x8 v8 = *(const bf16x8*)(qkv + kb[p] + h * 64 + 256);
            float s = 0.f;
            #pragma unroll
            for (int j = 0; j < 8; ++j) s += qf[j] * b2f(k8[j]);
            s += __shfl_xor(s, 1, 64);
            s += __shfl_xor(s, 2, 64);
            s += __shfl_xor(s, 4, 64);
            sc[p] = valid[p] ? s * 0.125f : -1e30f;
            #pragma unroll
            for (int j = 0; j < 8; ++j) vf[p][j] = b2f(v8[j]);  // invalid slots get p=0
        }
        float mx = fmaxf(sc[0], sc[1]);
        mx = fmaxf(mx, __shfl_xor(mx, 8, 64));
        mx = fmaxf(mx, __shfl_xor(mx, 16, 64));
        mx = fmaxf(mx, __shfl_xor(mx, 32, 64));
        const float p0 = __expf(sc[0] - mx);
        const float p1 = __expf(sc[1] - mx);
        float l = p0 + p1;
        l += __shfl_xor(l, 8, 64);
        l += __shfl_xor(l, 16, 64);
        l += __shfl_xor(l, 32, 64);

        float o8[8];
        #pragma unroll
        for (int j = 0; j < 8; ++j) o8[j] = p0 * vf[0][j] + p1 * vf[1][j];
        #pragma unroll
        for (int j = 0; j < 8; ++j) {
            o8[j] += __shfl_xor(o8[j], 8, 64);
            o8[j] += __shfl_xor(o8[j], 16, 64);
            o8[j] += __shfl_xor(o8[j], 32, 64);
        }
        if (n == 0) {
            const float rl = 1.f / l;
            bf16x8 r;
            #pragma unroll
            for (int j = 0; j < 8; ++j) r[j] = f2b(o8[j] * rl);
            *(bf16x8*)(ctx + ob + h * 64) = r;
        }
    }
}

// ---------------- fused proj GEMM: A = [q | c | |q-c| | q*c], K=1024, BK=64, bf16 out ----------------
__global__ __launch_bounds__(256) void proj_gemm_fused(const __hip_bfloat16* __restrict__ X,
                                                       const __hip_bfloat16* __restrict__ C2,
                                                       const __hip_bfloat16* __restrict__ W,
                                                       const float* __restrict__ bias,
                                                       __hip_bfloat16* __restrict__ Y) {
    __shared__ __align__(16) short As[128 * 64];
    __shared__ __align__(16) short Bs[128 * 64];
    const int tid = threadIdx.x;
    const int m0 = blockIdx.x * 128;
    const int n0 = blockIdx.y * 128;
    const int wave = tid >> 6, lane = tid & 63;
    const int wm = (wave >> 1) * 64;
    const int wn = (wave & 1) * 64;
    const int fm = lane & 15;
    const int fq = lane >> 4;

    f32x4 acc[4][4] = {};

    for (int k0 = 0; k0 < 1024; k0 += 64) {
        const int g = k0 >> 8;        // uniform group (64 | 256)
        const int cb = k0 & 255;
        #pragma unroll
        for (int v = 0; v < 4; ++v) {
            const int qbu = v * 256 + wave * 64;
            const int q = qbu + lane;
            const int r = q >> 3;
            const int cs = (q & 7) ^ (r & 7);
            async_copy16(W + (size_t)(n0 + r) * 1024 + k0 + cs * 8, &Bs[qbu * 8]);
        }
        if (g == 0) {
            #pragma unroll
            for (int v = 0; v < 4; ++v) {
                const int qbu = v * 256 + wave * 64;
                const int q = qbu + lane;
                const int r = q >> 3;
                const int cs = (q & 7) ^ (r & 7);
                async_copy16(X + (size_t)(m0 + r) * 256 + cb + cs * 8, &As[qbu * 8]);
            }
        } else if (g == 1) {
            #pragma unroll
            for (int v = 0; v < 4; ++v) {
                const int qbu = v * 256 + wave * 64;
                const int q = qbu + lane;
                const int r = q >> 3;
                const int cs = (q & 7) ^ (r & 7);
                async_copy16(C2 + (size_t)(m0 + r) * 256 + cb + cs * 8, &As[qbu * 8]);
            }
        } else {
            #pragma unroll
            for (int v = 0; v < 4; ++v) {
                const int q = v * 256 + tid;
                const int r = q >> 3;
                const int cs = (q & 7) ^ (r & 7);
                const size_t abase = (size_t)(m0 + r) * 256 + cb + cs * 8;
                int4 qraw = *(const int4*)(X + abase);
                int4 craw = *(const int4*)(C2 + abase);
                const short* qs = (const short*)&qraw;
                const short* cw = (const short*)&craw;
                short tmp[8];
                #pragma unroll
                for (int j = 0; j < 8; ++j) {
                    const float qv = b2f(qs[j]), cv = b2f(cw[j]);
                    tmp[j] = f2b(g == 2 ? fabsf(qv - cv) : qv * cv);
                }
                *(int4*)(&As[q * 8]) = *(int4*)tmp;
            }
        }
        __syncthreads();
        #pragma unroll
        for (int kk = 0; kk < 2; ++kk) {
            bf16x8 af[4], bw[4];
            #pragma unroll
            for (int i = 0; i < 4; ++i) {
                const int row = wm + i * 16 + fm;
                af[i] = *(const bf16x8*)(&As[row * 64 + (((fq + kk * 4) ^ (fm & 7)) * 8)]);
            }
            #pragma unroll
            for (int j = 0; j < 4; ++j) {
                const int row = wn + j * 16 + fm;
                bw[j] = *(const bf16x8*)(&Bs[row * 64 + (((fq + kk * 4) ^ (fm & 7)) * 8)]);
            }
            #pragma unroll
            for (int i = 0; i < 4; ++i)
                #pragma unroll
                for (int j = 0; j < 4; ++j)
                    acc[i][j] = __builtin_amdgcn_mfma_f32_16x16x32_bf16(af[i], bw[j], acc[i][j], 0, 0, 0);
        }
        __syncthreads();
    }
    #pragma unroll
    for (int j = 0; j < 4; ++j) {
        const int col = n0 + wn + j * 16 + fm;
        const float bv = bias[col];
        #pragma unroll
        for (int i = 0; i < 4; ++i) {
            #pragma unroll
            for (int r = 0; r < 4; ++r) {
                const int row = m0 + wm + i * 16 + fq * 4 + r;
                Y[(size_t)row * 256 + col] = __float2bfloat16(acc[i][j][r] + bv);
            }
        }
    }
}

// ---------------- LN + ReLU + transposed store (bf16 y) ----------------
__global__ __launch_bounds__(256) void ln_relu_store(const __hip_bfloat16* __restrict__ y,
                                                     const float* __restrict__ ln_g,
                                                     const float* __restrict__ ln_b,
                                                     float* __restrict__ out) {
    __shared__ float ys[32][257];
    __shared__ float mu_s[32], inv_s[32];
    const int tid = threadIdx.x;
    const int t0 = blockIdx.x * 32;
    const int b = t0 >> 12, sp = t0 & 4095;
    #pragma unroll
    for (int u = 0; u < 4; ++u) {
        const int o = tid + u * 256;           // octet index 0..1023
        const int tl = o >> 5, co = (o & 31) * 8;
        bf16x8 v8 = *(const bf16x8*)(y + (size_t)(t0 + tl) * 256 + co);
        #pragma unroll
        for (int j = 0; j < 8; ++j) ys[tl][co + j] = b2f(v8[j]);
    }
    __syncthreads();
    {
        const int tt = tid >> 3, seg = tid & 7;
        float s = 0.f, ss = 0.f;
        #pragma unroll
        for (int j = 0; j < 32; ++j) {
            const float v = ys[tt][seg * 32 + j];
            s += v; ss += v * v;
        }
        #pragma unroll
        for (int o = 1; o < 8; o <<= 1) {
            s += __shfl_xor(s, o, 8);
            ss += __shfl_xor(ss, o, 8);
        }
        if (seg == 0) {
            const float mu = s * (1.f / 256.f);
            const float var = ss * (1.f / 256.f) - mu * mu;
            mu_s[tt] = mu;
            inv_s[tt] = rsqrtf(var + 1e-5f);
        }
    }
    __syncthreads();
    const int tl = tid & 31, j0 = tid >> 5;
    const float mu = mu_s[tl], inv = inv_s[tl];
    #pragma unroll
    for (int u = 0; u < 32; ++u) {
        const int j = j0 + u * 8;
        const float v = (ys[tl][j] - mu) * inv * ln_g[j] + ln_b[j];
        out[((size_t)(b * 256 + j) << 12) + sp + tl] = fmaxf(v, 0.f);
    }
}

extern "C" void kernel_launch(void* const* d_in, const int* in_sizes, int n_in,
                              void* d_out, int out_size, void* d_ws, size_t ws_size,
                              hipStream_t stream) {
    (void)in_sizes; (void)n_in; (void)out_size; (void)ws_size;
    const float* feat   = (const float*)d_in[0];
    const float* in_w   = (const float*)d_in[1];
    const float* in_b   = (const float*)d_in[2];
    const float* out_w  = (const float*)d_in[3];
    const float* out_b  = (const float*)d_in[4];
    const float* proj_w = (const float*)d_in[5];
    const float* proj_b = (const float*)d_in[6];
    const float* ln_g   = (const float*)d_in[7];
    const float* ln_b   = (const float*)d_in[8];
    float* out = (float*)d_out;

    char* ws = (char*)d_ws;
    __hip_bfloat16* Xbf  = (__hip_bfloat16*)(ws);
    __hip_bfloat16* wbf  = (__hip_bfloat16*)(ws + (size_t)(16) * (1 << 20));
    __hip_bfloat16* qkv  = (__hip_bfloat16*)(ws + (size_t)(17) * (1 << 20));
    __hip_bfloat16* yb   = (__hip_bfloat16*)(ws + (size_t)(17) * (1 << 20)); // aliases dead qkv
    __hip_bfloat16* ctx  = (__hip_bfloat16*)(ws + (size_t)(65) * (1 << 20));
    __hip_bfloat16* ctx2 = (__hip_bfloat16*)(ws + (size_t)(81) * (1 << 20));
    __hip_bfloat16* in_wbf   = wbf;
    __hip_bfloat16* out_wbf  = wbf + 196608;
    __hip_bfloat16* proj_wbf = wbf + 262144;

    transpose_cast<<<dim3(128, 8, 8), 256, 0, stream>>>(feat, Xbf);
    cast_weights  <<<1024, 256, 0, stream>>>(in_w, out_w, proj_w, wbf);
    mfma_gemm<256, true><<<dim3(256, 6), 256, 0, stream>>>(Xbf, in_wbf, in_b, qkv, 768);
    attn_kernel   <<<NTOK / 4, 256, 0, stream>>>(qkv, ctx);
    mfma_gemm<256, true><<<dim3(256, 2), 256, 0, stream>>>(ctx, out_wbf, out_b, ctx2, 256);
    proj_gemm_fused<<<dim3(256, 2), 256, 0, stream>>>(Xbf, ctx2, proj_wbf, proj_b, yb);
    ln_relu_store <<<NTOK / 32, 256, 0, stream>>>(yb, ln_g, ln_b, out);
}

// Round 7
// 215.744 us; speedup vs baseline: 7.4932x; 1.0539x over previous
//
#include <hip/hip_runtime.h>
#include <hip/hip_bf16.h>

// ContralateralAttention, round 6: transpose-reduce attn, proj GEMM + fused LN.
// Tokens: t = b*4096 + y*64 + x (x in [0,64)), 32768 total.
// ws layout (MB), lifetime-packed:
//   Xbf   [  0, 16)   32768x256  bf16
//   wbf   [ 16, 17)   in_w | out_w | proj_w bf16
//   qkv   [ 17, 65)   32768x768  bf16   (dead after attn)
//   ctx   [ 65, 81)   32768x256  bf16
//   ctx2  [ 81, 97)   32768x256  bf16

#define NTOK 32768

using bf16x8 = __attribute__((ext_vector_type(8))) short;
using f32x4  = __attribute__((ext_vector_type(4))) float;

__device__ __forceinline__ float b2f(short s) {
    unsigned u = ((unsigned)(unsigned short)s) << 16;
    union { unsigned u; float f; } c; c.u = u; return c.f;
}
__device__ __forceinline__ short f2b(float f) {
    __hip_bfloat16 h = __float2bfloat16(f);
    return *(short*)&h;
}
__device__ __forceinline__ void async_copy16(const void* g, void* l) {
    __builtin_amdgcn_global_load_lds(
        (const __attribute__((address_space(1))) unsigned int*)g,
        (__attribute__((address_space(3))) unsigned int*)l, 16, 0, 0);
}

// ---------------- prep: feat (b,c,sp) f32 -> Xbf (t, c) bf16 ----------------
__global__ __launch_bounds__(256) void transpose_cast(const float* __restrict__ feat,
                                                      __hip_bfloat16* __restrict__ X) {
    __shared__ float tile[32][33];
    const int b  = blockIdx.z;
    const int c0 = blockIdx.y * 32;
    const int sp0 = blockIdx.x * 32;
    const int tid = threadIdx.x;
    const int col = tid & 31, rowg = tid >> 5;
    #pragma unroll
    for (int u = 0; u < 4; ++u) {
        int cl = rowg + u * 8;
        tile[cl][col] = feat[((size_t)(b * 256 + c0 + cl) << 12) + sp0 + col];
    }
    __syncthreads();
    #pragma unroll
    for (int u = 0; u < 4; ++u) {
        int spl = rowg + u * 8;
        X[(size_t)(b * 4096 + sp0 + spl) * 256 + c0 + col] = __float2bfloat16(tile[col][spl]);
    }
}

// ---------------- prep: cast weights to bf16 ----------------
__global__ __launch_bounds__(256) void cast_weights(const float* __restrict__ in_w,
                                                    const float* __restrict__ out_w,
                                                    const float* __restrict__ proj_w,
                                                    __hip_bfloat16* __restrict__ wbf) {
    const int i = blockIdx.x * 256 + threadIdx.x;
    if (i < 196608) wbf[i] = __float2bfloat16(in_w[i]);
    if (i < 65536)  wbf[196608 + i] = __float2bfloat16(out_w[i]);
    if (i < 262144) wbf[262144 + i] = __float2bfloat16(proj_w[i]);
}

// ---------------- MFMA GEMM, BK=64, global_load_lds staging (qkv / outproj) ----------------
template <int KDIM, bool OUT_BF16>
__global__ __launch_bounds__(256) void mfma_gemm(const __hip_bfloat16* __restrict__ A,
                                                 const __hip_bfloat16* __restrict__ W,
                                                 const float* __restrict__ bias,
                                                 void* __restrict__ C, int Ntot) {
    __shared__ __align__(16) short As[128 * 64];
    __shared__ __align__(16) short Bs[128 * 64];
    const int tid = threadIdx.x;
    const int m0 = blockIdx.x * 128;
    const int n0 = blockIdx.y * 128;
    const int wave = tid >> 6, lane = tid & 63;
    const int wm = (wave >> 1) * 64;
    const int wn = (wave & 1) * 64;
    const int fm = lane & 15;
    const int fq = lane >> 4;

    f32x4 acc[4][4] = {};

    for (int k0 = 0; k0 < KDIM; k0 += 64) {
        #pragma unroll
        for (int v = 0; v < 4; ++v) {
            const int qb = v * 256 + wave * 64;
            const int q = qb + lane;
            const int r = q >> 3;
            const int cs = (q & 7) ^ (r & 7);
            async_copy16(A + (size_t)(m0 + r) * KDIM + k0 + cs * 8, &As[qb * 8]);
            async_copy16(W + (size_t)(n0 + r) * KDIM + k0 + cs * 8, &Bs[qb * 8]);
        }
        __syncthreads();
        #pragma unroll
        for (int kk = 0; kk < 2; ++kk) {
            bf16x8 af[4], bw[4];
            #pragma unroll
            for (int i = 0; i < 4; ++i) {
                const int row = wm + i * 16 + fm;
                af[i] = *(const bf16x8*)(&As[row * 64 + (((fq + kk * 4) ^ (fm & 7)) * 8)]);
            }
            #pragma unroll
            for (int j = 0; j < 4; ++j) {
                const int row = wn + j * 16 + fm;
                bw[j] = *(const bf16x8*)(&Bs[row * 64 + (((fq + kk * 4) ^ (fm & 7)) * 8)]);
            }
            #pragma unroll
            for (int i = 0; i < 4; ++i)
                #pragma unroll
                for (int j = 0; j < 4; ++j)
                    acc[i][j] = __builtin_amdgcn_mfma_f32_16x16x32_bf16(af[i], bw[j], acc[i][j], 0, 0, 0);
        }
        __syncthreads();
    }
    #pragma unroll
    for (int j = 0; j < 4; ++j) {
        const int col = n0 + wn + j * 16 + fm;
        const float bv = bias[col];
        #pragma unroll
        for (int i = 0; i < 4; ++i) {
            #pragma unroll
            for (int r = 0; r < 4; ++r) {
                const int row = m0 + wm + i * 16 + fq * 4 + r;
                const float v = acc[i][j][r] + bv;
                if (OUT_BF16)
                    ((__hip_bfloat16*)C)[(size_t)row * Ntot + col] = __float2bfloat16(v);
                else
                    ((float*)C)[(size_t)row * Ntot + col] = v;
            }
        }
    }
}

// ---------------- sparse attention: one wave per token, 4 heads serial ----------------
// lanes: n = lane&7 (neighbor slot), cg = lane>>3 (channel octet).
// pass0: (0,0),(0,-1),(0,1),(0,-2),(0,2),(-1,0),(-1,-1),(-1,1)
// pass1: (1,0),(1,-1),(1,1),(-2,0),(2,0)  [slots 5..7 invalid]
#define P0DY ((2u)|(2u<<3)|(2u<<6)|(2u<<9)|(2u<<12)|(1u<<15)|(1u<<18)|(1u<<21))
#define P0DX ((2u)|(1u<<3)|(3u<<6)|(0u<<9)|(4u<<12)|(2u<<15)|(1u<<18)|(3u<<21))
#define P1DY ((3u)|(3u<<3)|(3u<<6)|(0u<<9)|(4u<<12)|(2u<<15)|(2u<<18)|(2u<<21))
#define P1DX ((2u)|(1u<<3)|(3u<<6)|(2u<<9)|(2u<<12)|(2u<<15)|(2u<<18)|(2u<<21))

__global__ __launch_bounds__(256) void attn_kernel(const __hip_bfloat16* __restrict__ qkv,
                                                   __hip_bfloat16* __restrict__ ctx) {
    const int t = blockIdx.x * 4 + (threadIdx.x >> 6);
    const int lane = threadIdx.x & 63;
    const int n  = lane & 7;
    const int cg = lane >> 3;
    const int x6 = t & 63;
    const int yq = (t >> 6) & 63;
    const int b  = t >> 12;
    const int side = x6 >> 5;
    const int x = x6 & 31;

    bool valid[2];
    size_t kb[2];
    #pragma unroll
    for (int p = 0; p < 2; ++p) {
        const unsigned dyp = p ? P1DY : P0DY;
        const unsigned dxp = p ? P1DX : P0DX;
        const int sh = 3 * n;
        const int dy = (int)((dyp >> sh) & 7) - 2;
        const int dx = (int)((dxp >> sh) & 7) - 2;
        const int yy = yq + dy, xx = x + dx;
        valid[p] = (p == 0 || n < 5) && yy >= 0 && yy < 64 && xx >= 0 && xx < 32;
        const int xm = side ? (31 - xx) : (63 - xx);
        int tm = (b << 12) + (yy << 6) + xm;
        if (!valid[p]) tm = t;
        kb[p] = (size_t)tm * 768 + 256 + cg * 8;
    }
    const size_t qb = (size_t)t * 768 + cg * 8;
    const size_t ob = (size_t)t * 256;

    #pragma unroll
    for (int h = 0; h < 4; ++h) {
        float qf[8];
        {
            bf16x8 q8 = *(const bf16x8*)(qkv + qb + h * 64);
            #pragma unroll
            for (int j = 0; j < 8; ++j) qf[j] = b2f(q8[j]);
        }
        float sc[2];
        float vf[2][8];
        #pragma unroll
        for (int p = 0; p < 2; ++p) {
            bf16x8 k8 = *(const bf16x8*)(qkv + kb[p] + h * 64);
            bf16x8 v8 = *(const bf16x8*)(qkv + kb[p] + h * 64 + 256);
            float s = 0.f;
            #pragma unroll
            for (int j = 0; j < 8; ++j) s += qf[j] * b2f(k8[j]);
            // reduce over channel-octets (cg = lane bits 3..5)
            s += __shfl_xor(s, 8, 64);
            s += __shfl_xor(s, 16, 64);
            s += __shfl_xor(s, 32, 64);
            sc[p] = valid[p] ? s * 0.125f : -1e30f;
            #pragma unroll
            for (int j = 0; j < 8; ++j) vf[p][j] = b2f(v8[j]);
        }
        // max / sum over neighbor slots (n = lane bits 0..2)
        float mx = fmaxf(sc[0], sc[1]);
        mx = fmaxf(mx, __shfl_xor(mx, 1, 64));
        mx = fmaxf(mx, __shfl_xor(mx, 2, 64));
        mx = fmaxf(mx, __shfl_xor(mx, 4, 64));
        const float p0 = __expf(sc[0] - mx);
        const float p1 = __expf(sc[1] - mx);
        float l = p0 + p1;
        l += __shfl_xor(l, 1, 64);
        l += __shfl_xor(l, 2, 64);
        l += __shfl_xor(l, 4, 64);

        float o[8];
        #pragma unroll
        for (int j = 0; j < 8; ++j) o[j] = p0 * vf[0][j] + p1 * vf[1][j];
        // transpose-reduce over n: 3 stages, 7 shuffles; lane ends with channel j == n.
        float r4[4];
        #pragma unroll
        for (int i = 0; i < 4; ++i) {
            const float a = o[2 * i], bb = o[2 * i + 1];
            const float mine = (n & 1) ? bb : a;
            const float theirs = (n & 1) ? a : bb;
            r4[i] = mine + __shfl_xor(theirs, 1, 64);
        }
        float r2[2];
        #pragma unroll
        for (int i = 0; i < 2; ++i) {
            const float a = r4[2 * i], bb = r4[2 * i + 1];
            const float mine = (n & 2) ? bb : a;
            const float theirs = (n & 2) ? a : bb;
            r2[i] = mine + __shfl_xor(theirs, 2, 64);
        }
        float ov;
        {
            const float a = r2[0], bb = r2[1];
            const float mine = (n & 4) ? bb : a;
            const float theirs = (n & 4) ? a : bb;
            ov = mine + __shfl_xor(theirs, 4, 64);
        }
        // lane holds channel cg*8 + n == lane; coalesced 128B store, all lanes.
        ctx[ob + h * 64 + lane] = __float2bfloat16(ov / l);
    }
}

// ---------------- proj GEMM + LN + ReLU + transposed store ----------------
// Tile M=64 x N=256 (full LN row in-block), K=1024 (A = [q|c||q-c||q*c] on the fly), BK=64.
__global__ __launch_bounds__(256) void proj_ln_fused(const __hip_bfloat16* __restrict__ X,
                                                     const __hip_bfloat16* __restrict__ C2,
                                                     const __hip_bfloat16* __restrict__ W,
                                                     const float* __restrict__ bias,
                                                     const float* __restrict__ ln_g,
                                                     const float* __restrict__ ln_b,
                                                     float* __restrict__ out) {
    __shared__ __align__(16) short smem[20480];   // 40 KB: staging / epilogue union
    __shared__ float mu_s[64], inv_s[64];
    short* As = smem;          // 64 x 64  (4096 shorts)
    short* Bs = smem + 4096;   // 256 x 64 (16384 shorts)
    const int tid = threadIdx.x;
    const int m0 = blockIdx.x * 64;
    const int b = m0 >> 12, sp0 = m0 & 4095;
    const int wave = tid >> 6, lane = tid & 63;
    const int wn = wave * 64;
    const int fm = lane & 15;
    const int fq = lane >> 4;

    f32x4 acc[4][4] = {};

    for (int k0 = 0; k0 < 1024; k0 += 64) {
        const int g = k0 >> 8;
        const int cb = k0 & 255;
        // B: 256x64 = 2048 chunks, 8 DMA rounds
        #pragma unroll
        for (int v = 0; v < 8; ++v) {
            const int qbu = v * 256 + wave * 64;
            const int q = qbu + lane;
            const int r = q >> 3;
            const int cs = (q & 7) ^ (r & 7);
            async_copy16(W + (size_t)r * 1024 + k0 + cs * 8, &Bs[qbu * 8]);
        }
        // A: 64x64 = 512 chunks, 2 rounds
        if (g == 0) {
            #pragma unroll
            for (int v = 0; v < 2; ++v) {
                const int qbu = v * 256 + wave * 64;
                const int q = qbu + lane;
                const int r = q >> 3;
                const int cs = (q & 7) ^ (r & 7);
                async_copy16(X + (size_t)(m0 + r) * 256 + cb + cs * 8, &As[qbu * 8]);
            }
        } else if (g == 1) {
            #pragma unroll
            for (int v = 0; v < 2; ++v) {
                const int qbu = v * 256 + wave * 64;
                const int q = qbu + lane;
                const int r = q >> 3;
                const int cs = (q & 7) ^ (r & 7);
                async_copy16(C2 + (size_t)(m0 + r) * 256 + cb + cs * 8, &As[qbu * 8]);
            }
        } else {
            #pragma unroll
            for (int v = 0; v < 2; ++v) {
                const int q = v * 256 + tid;
                const int r = q >> 3;
                const int cs = (q & 7) ^ (r & 7);
                const size_t abase = (size_t)(m0 + r) * 256 + cb + cs * 8;
                int4 qraw = *(const int4*)(X + abase);
                int4 craw = *(const int4*)(C2 + abase);
                const short* qs = (const short*)&qraw;
                const short* cw = (const short*)&craw;
                short tmp[8];
                #pragma unroll
                for (int j = 0; j < 8; ++j) {
                    const float qv = b2f(qs[j]), cv = b2f(cw[j]);
                    tmp[j] = f2b(g == 2 ? fabsf(qv - cv) : qv * cv);
                }
                *(int4*)(&As[q * 8]) = *(int4*)tmp;
            }
        }
        __syncthreads();
        #pragma unroll
        for (int kk = 0; kk < 2; ++kk) {
            bf16x8 af[4], bw[4];
            #pragma unroll
            for (int i = 0; i < 4; ++i) {
                const int row = i * 16 + fm;
                af[i] = *(const bf16x8*)(&As[row * 64 + (((fq + kk * 4) ^ (fm & 7)) * 8)]);
            }
            #pragma unroll
            for (int j = 0; j < 4; ++j) {
                const int row = wn + j * 16 + fm;
                bw[j] = *(const bf16x8*)(&Bs[row * 64 + (((fq + kk * 4) ^ (fm & 7)) * 8)]);
            }
            #pragma unroll
            for (int i = 0; i < 4; ++i)
                #pragma unroll
                for (int j = 0; j < 4; ++j)
                    acc[i][j] = __builtin_amdgcn_mfma_f32_16x16x32_bf16(af[i], bw[j], acc[i][j], 0, 0, 0);
        }
        __syncthreads();
    }
    // ---- epilogue: y -> LDS (bf16, stride 266), LN, ReLU, transposed store ----
    short* ys = smem;   // 64 x 266 = 17024 shorts (staging dead)
    #pragma unroll
    for (int j = 0; j < 4; ++j) {
        const int col = wn + j * 16 + fm;
        const float bv = bias[col];
        #pragma unroll
        for (int i = 0; i < 4; ++i)
            #pragma unroll
            for (int r = 0; r < 4; ++r)
                ys[(i * 16 + fq * 4 + r) * 266 + col] = f2b(acc[i][j][r] + bv);
    }
    __syncthreads();
    {   // stats: 4 threads per row
        const int tt = tid >> 2, seg = tid & 3;
        float s = 0.f, ss = 0.f;
        #pragma unroll
        for (int j = 0; j < 64; ++j) {
            const float v = b2f(ys[tt * 266 + seg * 64 + j]);
            s += v; ss += v * v;
        }
        s += __shfl_xor(s, 1, 64);  ss += __shfl_xor(ss, 1, 64);
        s += __shfl_xor(s, 2, 64);  ss += __shfl_xor(ss, 2, 64);
        if (seg == 0) {
            const float mu = s * (1.f / 256.f);
            const float var = ss * (1.f / 256.f) - mu * mu;
            mu_s[tt] = mu;
            inv_s[tt] = rsqrtf(var + 1e-5f);
        }
    }
    __syncthreads();
    {   // normalize + relu + coalesced transposed store
        const int tl = tid & 63;       // token within block
        const int j0 = tid >> 6;       // 0..3
        const float mu = mu_s[tl], inv = inv_s[tl];
        #pragma unroll
        for (int u = 0; u < 64; ++u) {
            const int j = j0 * 64 + u;
            const float v = (b2f(ys[tl * 266 + j]) - mu) * inv * ln_g[j] + ln_b[j];
            out[((size_t)(b * 256 + j) << 12) + sp0 + tl] = fmaxf(v, 0.f);
        }
    }
}

extern "C" void kernel_launch(void* const* d_in, const int* in_sizes, int n_in,
                              void* d_out, int out_size, void* d_ws, size_t ws_size,
                              hipStream_t stream) {
    (void)in_sizes; (void)n_in; (void)out_size; (void)ws_size;
    const float* feat   = (const float*)d_in[0];
    const float* in_w   = (const float*)d_in[1];
    const float* in_b   = (const float*)d_in[2];
    const float* out_w  = (const float*)d_in[3];
    const float* out_b  = (const float*)d_in[4];
    const float* proj_w = (const float*)d_in[5];
    const float* proj_b = (const float*)d_in[6];
    const float* ln_g   = (const float*)d_in[7];
    const float* ln_b   = (const float*)d_in[8];
    float* out = (float*)d_out;

    char* ws = (char*)d_ws;
    __hip_bfloat16* Xbf  = (__hip_bfloat16*)(ws);
    __hip_bfloat16* wbf  = (__hip_bfloat16*)(ws + (size_t)(16) * (1 << 20));
    __hip_bfloat16* qkv  = (__hip_bfloat16*)(ws + (size_t)(17) * (1 << 20));
    __hip_bfloat16* ctx  = (__hip_bfloat16*)(ws + (size_t)(65) * (1 << 20));
    __hip_bfloat16* ctx2 = (__hip_bfloat16*)(ws + (size_t)(81) * (1 << 20));
    __hip_bfloat16* in_wbf   = wbf;
    __hip_bfloat16* out_wbf  = wbf + 196608;
    __hip_bfloat16* proj_wbf = wbf + 262144;

    transpose_cast<<<dim3(128, 8, 8), 256, 0, stream>>>(feat, Xbf);
    cast_weights  <<<1024, 256, 0, stream>>>(in_w, out_w, proj_w, wbf);
    mfma_gemm<256, true><<<dim3(256, 6), 256, 0, stream>>>(Xbf, in_wbf, in_b, qkv, 768);
    attn_kernel   <<<NTOK / 4, 256, 0, stream>>>(qkv, ctx);
    mfma_gemm<256, true><<<dim3(256, 2), 256, 0, stream>>>(ctx, out_wbf, out_b, ctx2, 256);
    proj_ln_fused <<<NTOK / 64, 256, 0, stream>>>(Xbf, ctx2, proj_wbf, proj_b,
                                                  ln_g, ln_b, out);
}

// Round 8
// 197.456 us; speedup vs baseline: 8.1871x; 1.0926x over previous
//
#include <hip/hip_runtime.h>
#include <hip/hip_bf16.h>

// ContralateralAttention, round 7: attn = r5 coalesced lane map + r6 transpose-reduce
// (re-wired to n in lane bits 3..5), no-max softmax, head-pair load hoisting.
// Tokens: t = b*4096 + y*64 + x (x in [0,64)), 32768 total.
// ws layout (MB), lifetime-packed:
//   Xbf   [  0, 16)   32768x256  bf16
//   wbf   [ 16, 17)   in_w | out_w | proj_w bf16
//   qkv   [ 17, 65)   32768x768  bf16   (dead after attn)
//   ctx   [ 65, 81)   32768x256  bf16
//   ctx2  [ 81, 97)   32768x256  bf16

#define NTOK 32768

using bf16x8 = __attribute__((ext_vector_type(8))) short;
using f32x4  = __attribute__((ext_vector_type(4))) float;

__device__ __forceinline__ float b2f(short s) {
    unsigned u = ((unsigned)(unsigned short)s) << 16;
    union { unsigned u; float f; } c; c.u = u; return c.f;
}
__device__ __forceinline__ short f2b(float f) {
    __hip_bfloat16 h = __float2bfloat16(f);
    return *(short*)&h;
}
__device__ __forceinline__ void async_copy16(const void* g, void* l) {
    __builtin_amdgcn_global_load_lds(
        (const __attribute__((address_space(1))) unsigned int*)g,
        (__attribute__((address_space(3))) unsigned int*)l, 16, 0, 0);
}

// ---------------- prep: feat (b,c,sp) f32 -> Xbf (t, c) bf16 ----------------
__global__ __launch_bounds__(256) void transpose_cast(const float* __restrict__ feat,
                                                      __hip_bfloat16* __restrict__ X) {
    __shared__ float tile[32][33];
    const int b  = blockIdx.z;
    const int c0 = blockIdx.y * 32;
    const int sp0 = blockIdx.x * 32;
    const int tid = threadIdx.x;
    const int col = tid & 31, rowg = tid >> 5;
    #pragma unroll
    for (int u = 0; u < 4; ++u) {
        int cl = rowg + u * 8;
        tile[cl][col] = feat[((size_t)(b * 256 + c0 + cl) << 12) + sp0 + col];
    }
    __syncthreads();
    #pragma unroll
    for (int u = 0; u < 4; ++u) {
        int spl = rowg + u * 8;
        X[(size_t)(b * 4096 + sp0 + spl) * 256 + c0 + col] = __float2bfloat16(tile[col][spl]);
    }
}

// ---------------- prep: cast weights to bf16 ----------------
__global__ __launch_bounds__(256) void cast_weights(const float* __restrict__ in_w,
                                                    const float* __restrict__ out_w,
                                                    const float* __restrict__ proj_w,
                                                    __hip_bfloat16* __restrict__ wbf) {
    const int i = blockIdx.x * 256 + threadIdx.x;
    if (i < 196608) wbf[i] = __float2bfloat16(in_w[i]);
    if (i < 65536)  wbf[196608 + i] = __float2bfloat16(out_w[i]);
    if (i < 262144) wbf[262144 + i] = __float2bfloat16(proj_w[i]);
}

// ---------------- MFMA GEMM, BK=64, global_load_lds staging (qkv / outproj) ----------------
template <int KDIM, bool OUT_BF16>
__global__ __launch_bounds__(256) void mfma_gemm(const __hip_bfloat16* __restrict__ A,
                                                 const __hip_bfloat16* __restrict__ W,
                                                 const float* __restrict__ bias,
                                                 void* __restrict__ C, int Ntot) {
    __shared__ __align__(16) short As[128 * 64];
    __shared__ __align__(16) short Bs[128 * 64];
    const int tid = threadIdx.x;
    const int m0 = blockIdx.x * 128;
    const int n0 = blockIdx.y * 128;
    const int wave = tid >> 6, lane = tid & 63;
    const int wm = (wave >> 1) * 64;
    const int wn = (wave & 1) * 64;
    const int fm = lane & 15;
    const int fq = lane >> 4;

    f32x4 acc[4][4] = {};

    for (int k0 = 0; k0 < KDIM; k0 += 64) {
        #pragma unroll
        for (int v = 0; v < 4; ++v) {
            const int qb = v * 256 + wave * 64;
            const int q = qb + lane;
            const int r = q >> 3;
            const int cs = (q & 7) ^ (r & 7);
            async_copy16(A + (size_t)(m0 + r) * KDIM + k0 + cs * 8, &As[qb * 8]);
            async_copy16(W + (size_t)(n0 + r) * KDIM + k0 + cs * 8, &Bs[qb * 8]);
        }
        __syncthreads();
        #pragma unroll
        for (int kk = 0; kk < 2; ++kk) {
            bf16x8 af[4], bw[4];
            #pragma unroll
            for (int i = 0; i < 4; ++i) {
                const int row = wm + i * 16 + fm;
                af[i] = *(const bf16x8*)(&As[row * 64 + (((fq + kk * 4) ^ (fm & 7)) * 8)]);
            }
            #pragma unroll
            for (int j = 0; j < 4; ++j) {
                const int row = wn + j * 16 + fm;
                bw[j] = *(const bf16x8*)(&Bs[row * 64 + (((fq + kk * 4) ^ (fm & 7)) * 8)]);
            }
            #pragma unroll
            for (int i = 0; i < 4; ++i)
                #pragma unroll
                for (int j = 0; j < 4; ++j)
                    acc[i][j] = __builtin_amdgcn_mfma_f32_16x16x32_bf16(af[i], bw[j], acc[i][j], 0, 0, 0);
        }
        __syncthreads();
    }
    #pragma unroll
    for (int j = 0; j < 4; ++j) {
        const int col = n0 + wn + j * 16 + fm;
        const float bv = bias[col];
        #pragma unroll
        for (int i = 0; i < 4; ++i) {
            #pragma unroll
            for (int r = 0; r < 4; ++r) {
                const int row = m0 + wm + i * 16 + fq * 4 + r;
                const float v = acc[i][j][r] + bv;
                if (OUT_BF16)
                    ((__hip_bfloat16*)C)[(size_t)row * Ntot + col] = __float2bfloat16(v);
                else
                    ((float*)C)[(size_t)row * Ntot + col] = v;
            }
        }
    }
}

// ---------------- sparse attention: one wave/token, 4 heads (pairs), coalesced loads ----------------
// lanes: n = lane>>3 (neighbor slot, bits 3..5), cg = lane&7 (channel octet, bits 0..2).
// 8-lane groups (fixed n) load 128B contiguous K/V segments -> coalesced.
// pass0: (0,0),(0,-1),(0,1),(0,-2),(0,2),(-1,0),(-1,-1),(-1,1)
// pass1: (1,0),(1,-1),(1,1),(-2,0),(2,0)  [slots 5..7 invalid]
#define P0DY ((2u)|(2u<<3)|(2u<<6)|(2u<<9)|(2u<<12)|(1u<<15)|(1u<<18)|(1u<<21))
#define P0DX ((2u)|(1u<<3)|(3u<<6)|(0u<<9)|(4u<<12)|(2u<<15)|(1u<<18)|(3u<<21))
#define P1DY ((3u)|(3u<<3)|(3u<<6)|(0u<<9)|(4u<<12)|(2u<<15)|(2u<<18)|(2u<<21))
#define P1DX ((2u)|(1u<<3)|(3u<<6)|(2u<<9)|(2u<<12)|(2u<<15)|(2u<<18)|(2u<<21))

__global__ __launch_bounds__(256) void attn_kernel(const __hip_bfloat16* __restrict__ qkv,
                                                   __hip_bfloat16* __restrict__ ctx) {
    const int t = blockIdx.x * 4 + (threadIdx.x >> 6);
    const int lane = threadIdx.x & 63;
    const int n  = lane >> 3;
    const int cg = lane & 7;
    const int x6 = t & 63;
    const int yq = (t >> 6) & 63;
    const int b  = t >> 12;
    const int side = x6 >> 5;
    const int x = x6 & 31;

    bool valid[2];
    size_t kb[2];
    #pragma unroll
    for (int p = 0; p < 2; ++p) {
        const unsigned dyp = p ? P1DY : P0DY;
        const unsigned dxp = p ? P1DX : P0DX;
        const int sh = 3 * n;
        const int dy = (int)((dyp >> sh) & 7) - 2;
        const int dx = (int)((dxp >> sh) & 7) - 2;
        const int yy = yq + dy, xx = x + dx;
        valid[p] = (p == 0 || n < 5) && yy >= 0 && yy < 64 && xx >= 0 && xx < 32;
        const int xm = side ? (31 - xx) : (63 - xx);
        int tm = (b << 12) + (yy << 6) + xm;
        if (!valid[p]) tm = t;
        kb[p] = (size_t)tm * 768 + 256 + cg * 8;
    }
    const size_t qb = (size_t)t * 768 + cg * 8;
    const size_t ob = (size_t)t * 256;

    #pragma unroll
    for (int hp = 0; hp < 2; ++hp) {
        // hoist all loads for this head pair: 10 dwordx4 in flight
        bf16x8 q8[2], k8[2][2], v8[2][2];
        #pragma unroll
        for (int hh = 0; hh < 2; ++hh) {
            const int h = hp * 2 + hh;
            q8[hh] = *(const bf16x8*)(qkv + qb + h * 64);
            #pragma unroll
            for (int p = 0; p < 2; ++p) {
                k8[hh][p] = *(const bf16x8*)(qkv + kb[p] + h * 64);
                v8[hh][p] = *(const bf16x8*)(qkv + kb[p] + h * 64 + 256);
            }
        }
        #pragma unroll
        for (int hh = 0; hh < 2; ++hh) {
            float sc[2];
            #pragma unroll
            for (int p = 0; p < 2; ++p) {
                float s = 0.f;
                #pragma unroll
                for (int j = 0; j < 8; ++j) s += b2f(q8[hh][j]) * b2f(k8[hh][p][j]);
                // reduce over channel octets (cg = lane bits 0..2)
                s += __shfl_xor(s, 1, 64);
                s += __shfl_xor(s, 2, 64);
                s += __shfl_xor(s, 4, 64);
                sc[p] = valid[p] ? s * 0.125f : -1e30f;
            }
            // scores are O(1)-bounded: exp without max-subtraction is safe;
            // invalid slots: exp(-1e30) == 0 exactly.
            const float p0 = __expf(sc[0]);
            const float p1 = __expf(sc[1]);
            float l = p0 + p1;
            l += __shfl_xor(l, 8, 64);
            l += __shfl_xor(l, 16, 64);
            l += __shfl_xor(l, 32, 64);

            float o[8];
            #pragma unroll
            for (int j = 0; j < 8; ++j)
                o[j] = p0 * b2f(v8[hh][0][j]) + p1 * b2f(v8[hh][1][j]);
            // transpose-reduce over n (lane bits 3..5): 3 stages, 7 shuffles;
            // lane (n,cg) ends holding channel cg*8+n summed over all slots.
            float r4[4];
            #pragma unroll
            for (int i = 0; i < 4; ++i) {
                const float a = o[2 * i], bb = o[2 * i + 1];
                const float mine = (n & 1) ? bb : a;
                const float theirs = (n & 1) ? a : bb;
                r4[i] = mine + __shfl_xor(theirs, 8, 64);
            }
            float r2[2];
            #pragma unroll
            for (int i = 0; i < 2; ++i) {
                const float a = r2[0] * 0.f + r4[2 * i], bb = r4[2 * i + 1];
                const float mine = (n & 2) ? bb : a;
                const float theirs = (n & 2) ? a : bb;
                r2[i] = mine + __shfl_xor(theirs, 16, 64);
            }
            float ov;
            {
                const float a = r2[0], bb = r2[1];
                const float mine = (n & 4) ? bb : a;
                const float theirs = (n & 4) ? a : bb;
                ov = mine + __shfl_xor(theirs, 32, 64);
            }
            // permuted store within one 128B line
            ctx[ob + (hp * 2 + hh) * 64 + cg * 8 + n] = __float2bfloat16(ov / l);
        }
    }
}

// ---------------- proj GEMM + LN + ReLU + transposed store ----------------
// Tile M=64 x N=256 (full LN row in-block), K=1024 (A = [q|c||q-c||q*c] on the fly), BK=64.
__global__ __launch_bounds__(256) void proj_ln_fused(const __hip_bfloat16* __restrict__ X,
                                                     const __hip_bfloat16* __restrict__ C2,
                                                     const __hip_bfloat16* __restrict__ W,
                                                     const float* __restrict__ bias,
                                                     const float* __restrict__ ln_g,
                                                     const float* __restrict__ ln_b,
                                                     float* __restrict__ out) {
    __shared__ __align__(16) short smem[20480];   // 40 KB: staging / epilogue union
    __shared__ float mu_s[64], inv_s[64];
    short* As = smem;          // 64 x 64  (4096 shorts)
    short* Bs = smem + 4096;   // 256 x 64 (16384 shorts)
    const int tid = threadIdx.x;
    const int m0 = blockIdx.x * 64;
    const int b = m0 >> 12, sp0 = m0 & 4095;
    const int wave = tid >> 6, lane = tid & 63;
    const int wn = wave * 64;
    const int fm = lane & 15;
    const int fq = lane >> 4;

    f32x4 acc[4][4] = {};

    for (int k0 = 0; k0 < 1024; k0 += 64) {
        const int g = k0 >> 8;
        const int cb = k0 & 255;
        #pragma unroll
        for (int v = 0; v < 8; ++v) {
            const int qbu = v * 256 + wave * 64;
            const int q = qbu + lane;
            const int r = q >> 3;
            const int cs = (q & 7) ^ (r & 7);
            async_copy16(W + (size_t)r * 1024 + k0 + cs * 8, &Bs[qbu * 8]);
        }
        if (g == 0) {
            #pragma unroll
            for (int v = 0; v < 2; ++v) {
                const int qbu = v * 256 + wave * 64;
                const int q = qbu + lane;
                const int r = q >> 3;
                const int cs = (q & 7) ^ (r & 7);
                async_copy16(X + (size_t)(m0 + r) * 256 + cb + cs * 8, &As[qbu * 8]);
            }
        } else if (g == 1) {
            #pragma unroll
            for (int v = 0; v < 2; ++v) {
                const int qbu = v * 256 + wave * 64;
                const int q = qbu + lane;
                const int r = q >> 3;
                const int cs = (q & 7) ^ (r & 7);
                async_copy16(C2 + (size_t)(m0 + r) * 256 + cb + cs * 8, &As[qbu * 8]);
            }
        } else {
            #pragma unroll
            for (int v = 0; v < 2; ++v) {
                const int q = v * 256 + tid;
                const int r = q >> 3;
                const int cs = (q & 7) ^ (r & 7);
                const size_t abase = (size_t)(m0 + r) * 256 + cb + cs * 8;
                int4 qraw = *(const int4*)(X + abase);
                int4 craw = *(const int4*)(C2 + abase);
                const short* qs = (const short*)&qraw;
                const short* cw = (const short*)&craw;
                short tmp[8];
                #pragma unroll
                for (int j = 0; j < 8; ++j) {
                    const float qv = b2f(qs[j]), cv = b2f(cw[j]);
                    tmp[j] = f2b(g == 2 ? fabsf(qv - cv) : qv * cv);
                }
                *(int4*)(&As[q * 8]) = *(int4*)tmp;
            }
        }
        __syncthreads();
        #pragma unroll
        for (int kk = 0; kk < 2; ++kk) {
            bf16x8 af[4], bw[4];
            #pragma unroll
            for (int i = 0; i < 4; ++i) {
                const int row = i * 16 + fm;
                af[i] = *(const bf16x8*)(&As[row * 64 + (((fq + kk * 4) ^ (fm & 7)) * 8)]);
            }
            #pragma unroll
            for (int j = 0; j < 4; ++j) {
                const int row = wn + j * 16 + fm;
                bw[j] = *(const bf16x8*)(&Bs[row * 64 + (((fq + kk * 4) ^ (fm & 7)) * 8)]);
            }
            #pragma unroll
            for (int i = 0; i < 4; ++i)
                #pragma unroll
                for (int j = 0; j < 4; ++j)
                    acc[i][j] = __builtin_amdgcn_mfma_f32_16x16x32_bf16(af[i], bw[j], acc[i][j], 0, 0, 0);
        }
        __syncthreads();
    }
    // ---- epilogue: y -> LDS (bf16, stride 266), LN, ReLU, transposed store ----
    short* ys = smem;
    #pragma unroll
    for (int j = 0; j < 4; ++j) {
        const int col = wn + j * 16 + fm;
        const float bv = bias[col];
        #pragma unroll
        for (int i = 0; i < 4; ++i)
            #pragma unroll
            for (int r = 0; r < 4; ++r)
                ys[(i * 16 + fq * 4 + r) * 266 + col] = f2b(acc[i][j][r] + bv);
    }
    __syncthreads();
    {
        const int tt = tid >> 2, seg = tid & 3;
        float s = 0.f, ss = 0.f;
        #pragma unroll
        for (int j = 0; j < 64; ++j) {
            const float v = b2f(ys[tt * 266 + seg * 64 + j]);
            s += v; ss += v * v;
        }
        s += __shfl_xor(s, 1, 64);  ss += __shfl_xor(ss, 1, 64);
        s += __shfl_xor(s, 2, 64);  ss += __shfl_xor(ss, 2, 64);
        if (seg == 0) {
            const float mu = s * (1.f / 256.f);
            const float var = ss * (1.f / 256.f) - mu * mu;
            mu_s[tt] = mu;
            inv_s[tt] = rsqrtf(var + 1e-5f);
        }
    }
    __syncthreads();
    {
        const int tl = tid & 63;
        const int j0 = tid >> 6;
        const float mu = mu_s[tl], inv = inv_s[tl];
        #pragma unroll
        for (int u = 0; u < 64; ++u) {
            const int j = j0 * 64 + u;
            const float v = (b2f(ys[tl * 266 + j]) - mu) * inv * ln_g[j] + ln_b[j];
            out[((size_t)(b * 256 + j) << 12) + sp0 + tl] = fmaxf(v, 0.f);
        }
    }
}

extern "C" void kernel_launch(void* const* d_in, const int* in_sizes, int n_in,
                              void* d_out, int out_size, void* d_ws, size_t ws_size,
                              hipStream_t stream) {
    (void)in_sizes; (void)n_in; (void)out_size; (void)ws_size;
    const float* feat   = (const float*)d_in[0];
    const float* in_w   = (const float*)d_in[1];
    const float* in_b   = (const float*)d_in[2];
    const float* out_w  = (const float*)d_in[3];
    const float* out_b  = (const float*)d_in[4];
    const float* proj_w = (const float*)d_in[5];
    const float* proj_b = (const float*)d_in[6];
    const float* ln_g   = (const float*)d_in[7];
    const float* ln_b   = (const float*)d_in[8];
    float* out = (float*)d_out;

    char* ws = (char*)d_ws;
    __hip_bfloat16* Xbf  = (__hip_bfloat16*)(ws);
    __hip_bfloat16* wbf  = (__hip_bfloat16*)(ws + (size_t)(16) * (1 << 20));
    __hip_bfloat16* qkv  = (__hip_bfloat16*)(ws + (size_t)(17) * (1 << 20));
    __hip_bfloat16* ctx  = (__hip_bfloat16*)(ws + (size_t)(65) * (1 << 20));
    __hip_bfloat16* ctx2 = (__hip_bfloat16*)(ws + (size_t)(81) * (1 << 20));
    __hip_bfloat16* in_wbf   = wbf;
    __hip_bfloat16* out_wbf  = wbf + 196608;
    __hip_bfloat16* proj_wbf = wbf + 262144;

    transpose_cast<<<dim3(128, 8, 8), 256, 0, stream>>>(feat, Xbf);
    cast_weights  <<<1024, 256, 0, stream>>>(in_w, out_w, proj_w, wbf);
    mfma_gemm<256, true><<<dim3(256, 6), 256, 0, stream>>>(Xbf, in_wbf, in_b, qkv, 768);
    attn_kernel   <<<NTOK / 4, 256, 0, stream>>>(qkv, ctx);
    mfma_gemm<256, true><<<dim3(256, 2), 256, 0, stream>>>(ctx, out_wbf, out_b, ctx2, 256);
    proj_ln_fused <<<NTOK / 64, 256, 0, stream>>>(Xbf, ctx2, proj_wbf, proj_b,
                                                  ln_g, ln_b, out);
}